// Round 9
// baseline (291.340 us; speedup 1.0000x reference)
//
#include <hip/hip_runtime.h>
#include <hip/hip_fp16.h>

#define NEG_SLOPE 0.2f
#define BN_EPS 1e-5f

constexpr int D = 64;   // feature dim
constexpr int H = 4;    // heads

typedef _Float16 half4_t __attribute__((ext_vector_type(4)));
typedef _Float16 half8_t __attribute__((ext_vector_type(8)));
typedef float f32x4_t __attribute__((ext_vector_type(4)));
typedef int i32x4 __attribute__((ext_vector_type(4)));  // native vec for nontemporal builtins

// 16-B edge record: {idx, pad, w[4]} — idx is rank (edge-order pass) or src
// (CSR-order pass); w = per-edge softmax numerators for the 4 heads.
union Rec {
    i32x4 i4;
    struct { int idx; int pad; half4_t w; } f;
};

#define MFMA16(a, b, c) __builtin_amdgcn_mfma_f32_16x16x32_f16(a, b, c, 0, 0, 0)

__device__ inline float lrelu(float v) { return (v >= 0.f) ? v : NEG_SLOPE * v; }

// load 8 consecutive fp32, split into fp16 hi + lo halves (hi+lo ~ fp32)
__device__ inline void split8(const float* p, bool ok, half8_t& hi, half8_t& lo) {
    float f[8];
    if (ok) {
        float4 a = *(const float4*)p;
        float4 b = *(const float4*)(p + 4);
        f[0] = a.x; f[1] = a.y; f[2] = a.z; f[3] = a.w;
        f[4] = b.x; f[5] = b.y; f[6] = b.z; f[7] = b.w;
    } else {
        #pragma unroll
        for (int j = 0; j < 8; j++) f[j] = 0.f;
    }
    #pragma unroll
    for (int j = 0; j < 8; j++) {
        _Float16 h = (_Float16)f[j];
        hi[j] = h;
        lo[j] = (_Float16)(f[j] - (float)h);
    }
}

// one-time weight split: W_lin (4096) and W_gat (16384) -> fp16 hi/lo tables
__global__ __launch_bounds__(256) void k_prep(const float* __restrict__ W_lin,
                                              const float* __restrict__ W_gat,
                                              _Float16* __restrict__ wlin_hi,
                                              _Float16* __restrict__ wlin_lo,
                                              _Float16* __restrict__ wgat_hi,
                                              _Float16* __restrict__ wgat_lo) {
    int idx = blockIdx.x * 256 + threadIdx.x;
    if (idx < 4096) {
        float v = W_lin[idx];
        _Float16 h = (_Float16)v;
        wlin_hi[idx] = h;
        wlin_lo[idx] = (_Float16)(v - (float)h);
    }
    int j = idx - 4096;
    if (j >= 0 && j < 16384) {
        float v = W_gat[j];
        _Float16 h = (_Float16)v;
        wgat_hi[j] = h;
        wgat_lo[j] = (_Float16)(v - (float)h);
    }
}

// Fused MFMA node kernel: x1 = prelu(x @ W_lin^T + b_lin); h = x1 @ W_gat^T
// (split-fp16 MFMA ~ fp32 accuracy); h stored fp16 layout [n][d][head];
// attention dots from accumulator registers. Also zeroes deg slice / sums /
// gcount (runs before any kernel that uses them).
__global__ __launch_bounds__(256) void k_node(
    const float* __restrict__ x,
    const _Float16* __restrict__ wlin_hi, const _Float16* __restrict__ wlin_lo,
    const float* __restrict__ b_lin, const float* __restrict__ prelu_w,
    const _Float16* __restrict__ wgat_hi, const _Float16* __restrict__ wgat_lo,
    const float* __restrict__ att_src, const float* __restrict__ att_dst,
    _Float16* __restrict__ hh, float* __restrict__ asrc_ws,
    float* __restrict__ adst_ws, int* __restrict__ deg,
    float* __restrict__ sums, int* __restrict__ gcount, int N)
{
    __shared__ _Float16 h_lds[32 * 256];   // 16 KB, [m][d*4+head]
    __shared__ _Float16 x1hi[32 * 72];     // 4.5 KB, row-padded (72 halves=144B)
    __shared__ _Float16 x1lo[32 * 72];

    const int t = threadIdx.x;
    const int w = t >> 6;    // wave id == head
    const int l = t & 63;
    const int li = l & 15;
    const int lq = l >> 4;
    const int base = blockIdx.x * 32;
    const int nvalid = min(32, N - base);

    // fused init: zero this block's deg slice; block 0 zeroes sums + gcount
    if (t < nvalid) deg[base + t] = 0;
    if (blockIdx.x == 0) {
        if (t < 2 * D) sums[t] = 0.f;
        if (t == 0) *gcount = 0;
    }

    // ---- stage A: MFMA x @ W_lin^T for cols 16w..16w+15 ----
    f32x4_t accA[2] = {};
    half8_t blh[2], bll[2];
    {
        const int n = 16 * w + li;
        #pragma unroll
        for (int ks = 0; ks < 2; ks++) {
            blh[ks] = *(const half8_t*)(wlin_hi + n * 64 + 32 * ks + 8 * lq);
            bll[ks] = *(const half8_t*)(wlin_lo + n * 64 + 32 * ks + 8 * lq);
        }
    }
    #pragma unroll
    for (int mt = 0; mt < 2; mt++) {
        const int row = base + 16 * mt + li;
        const bool ok = row < N;
        #pragma unroll
        for (int ks = 0; ks < 2; ks++) {
            half8_t ah, al;
            split8(x + (size_t)row * 64 + 32 * ks + 8 * lq, ok, ah, al);
            accA[mt] = MFMA16(ah, blh[ks], accA[mt]);
            accA[mt] = MFMA16(al, blh[ks], accA[mt]);
            accA[mt] = MFMA16(ah, bll[ks], accA[mt]);
        }
    }
    // epilogue A: +bias, prelu, split to fp16 hi/lo in LDS
    {
        const int n = 16 * w + li;
        const float bl = b_lin[n];
        const float pw = prelu_w[n];
        #pragma unroll
        for (int mt = 0; mt < 2; mt++) {
            #pragma unroll
            for (int r = 0; r < 4; r++) {
                const int m = 16 * mt + lq * 4 + r;
                float v = accA[mt][r] + bl;
                v = (v >= 0.f) ? v : pw * v;
                _Float16 hi = (_Float16)v;
                x1hi[m * 72 + n] = hi;
                x1lo[m * 72 + n] = (_Float16)(v - (float)hi);
            }
        }
    }
    __syncthreads();

    // ---- stage B: MFMA x1 @ W_gat^T for cols 64w..64w+63 ----
    half8_t xah[2][2], xal[2][2];
    #pragma unroll
    for (int mt = 0; mt < 2; mt++) {
        #pragma unroll
        for (int ks = 0; ks < 2; ks++) {
            const int off = (16 * mt + li) * 72 + 32 * ks + 8 * lq;
            xah[mt][ks] = *(const half8_t*)(&x1hi[off]);
            xal[mt][ks] = *(const half8_t*)(&x1lo[off]);
        }
    }
    f32x4_t accB[2][4] = {};
    #pragma unroll
    for (int nt = 0; nt < 4; nt++) {
        half8_t wh[2], wl[2];
        const int c = 64 * w + 16 * nt + li;
        #pragma unroll
        for (int ks = 0; ks < 2; ks++) {
            wh[ks] = *(const half8_t*)(wgat_hi + (size_t)c * 64 + 32 * ks + 8 * lq);
            wl[ks] = *(const half8_t*)(wgat_lo + (size_t)c * 64 + 32 * ks + 8 * lq);
        }
        #pragma unroll
        for (int mt = 0; mt < 2; mt++) {
            #pragma unroll
            for (int ks = 0; ks < 2; ks++) {
                accB[mt][nt] = MFMA16(xah[mt][ks], wh[ks], accB[mt][nt]);
                accB[mt][nt] = MFMA16(xal[mt][ks], wh[ks], accB[mt][nt]);
                accB[mt][nt] = MFMA16(xah[mt][ks], wl[ks], accB[mt][nt]);
            }
        }
    }

    // ---- attention dots from registers: a[n][w] = sum_d h[n][w][d]*att[w][d]
    {
        float asv[4], adv[4];
        #pragma unroll
        for (int nt = 0; nt < 4; nt++) {
            const int c = 64 * w + 16 * nt + li;
            asv[nt] = att_src[c];
            adv[nt] = att_dst[c];
        }
        #pragma unroll
        for (int mt = 0; mt < 2; mt++) {
            #pragma unroll
            for (int r = 0; r < 4; r++) {
                float s = 0.f, dsum = 0.f;
                #pragma unroll
                for (int nt = 0; nt < 4; nt++) {
                    s += accB[mt][nt][r] * asv[nt];
                    dsum += accB[mt][nt][r] * adv[nt];
                }
                #pragma unroll
                for (int off = 1; off < 16; off <<= 1) {
                    s += __shfl_xor(s, off, 64);
                    dsum += __shfl_xor(dsum, off, 64);
                }
                if (li == 0) {
                    const int m = 16 * mt + lq * 4 + r;
                    if (m < nvalid) {
                        asrc_ws[(size_t)(base + m) * H + w] = s;
                        adst_ws[(size_t)(base + m) * H + w] = dsum;
                    }
                }
            }
        }
    }

    // ---- h -> LDS in [m][d*4+head] layout, then coalesced global write ----
    #pragma unroll
    for (int mt = 0; mt < 2; mt++) {
        #pragma unroll
        for (int nt = 0; nt < 4; nt++) {
            #pragma unroll
            for (int r = 0; r < 4; r++) {
                const int m = 16 * mt + lq * 4 + r;
                const int d = 16 * nt + li;
                h_lds[m * 256 + d * 4 + w] = (_Float16)accB[mt][nt][r];
            }
        }
    }
    __syncthreads();
    {
        const int chunks = nvalid * 32;  // 8 halves (16B) per chunk
        const uint4* src = (const uint4*)h_lds;
        uint4* dst = (uint4*)(hh + (size_t)base * 256);
        for (int i = t; i < chunks; i += 256) dst[i] = src[i];
    }
}

// ---- hist + rank + per-edge softmax numerators (edge-order, coalesced) ----
// atomicAdd's return IS the edge's rank within its dst -> no second atomic
// pass needed. {rank, w} written coalesced, non-temporal (read-once stream).
__global__ __launch_bounds__(256) void k_hist_w(const int* __restrict__ ei,
                                                int* __restrict__ deg,
                                                const float* __restrict__ asrc,
                                                const float* __restrict__ adst,
                                                i32x4* __restrict__ rtmp,
                                                int E) {
    int e = blockIdx.x * 256 + threadIdx.x;
    if (e >= E) return;
    int s = ei[e];
    int d = ei[E + e];
    int rank = atomicAdd(&deg[d], 1);
    float4 a = *(const float4*)(asrc + (size_t)s * H);
    float4 b = *(const float4*)(adst + (size_t)d * H);
    Rec r;
    r.f.idx = rank;
    r.f.pad = 0;
    r.f.w[0] = (_Float16)__expf(lrelu(a.x + b.x));
    r.f.w[1] = (_Float16)__expf(lrelu(a.y + b.y));
    r.f.w[2] = (_Float16)__expf(lrelu(a.z + b.z));
    r.f.w[3] = (_Float16)__expf(lrelu(a.w + b.w));
    __builtin_nontemporal_store(r.i4, &rtmp[e]);
}

// single-kernel offsets: per-block exclusive scan + one atomicAdd for the
// block's base (bucket order across blocks is irrelevant — only disjointness
// and per-dst contiguity matter).
__global__ __launch_bounds__(256) void k_offsets(const int* __restrict__ deg,
                                                 int* __restrict__ gcount,
                                                 int* __restrict__ offs, int N) {
    __shared__ int sm[256];
    __shared__ int sbase;
    int t = threadIdx.x;
    int idx = blockIdx.x * 256 + t;
    int v = (idx < N) ? deg[idx] : 0;
    sm[t] = v;
    __syncthreads();
    for (int off = 1; off < 256; off <<= 1) {
        int w = (t >= off) ? sm[t - off] : 0;
        __syncthreads();
        sm[t] += w;
        __syncthreads();
    }
    if (t == 255) sbase = atomicAdd(gcount, sm[255]);
    __syncthreads();
    if (idx < N) offs[idx] = sbase + sm[t] - v;  // exclusive within block + base
}

// atomic-free permute-scatter: pos = offs[dst] + rank (from k_hist_w).
// One random 16-B non-temporal store per edge (avoids RMW line fetch).
__global__ __launch_bounds__(256) void k_fill(const int* __restrict__ ei,
                                              const int* __restrict__ offs,
                                              const i32x4* __restrict__ rtmp,
                                              i32x4* __restrict__ recs, int E) {
    int e = blockIdx.x * 256 + threadIdx.x;
    if (e >= E) return;
    int d = ei[E + e];
    Rec r;
    r.i4 = __builtin_nontemporal_load(&rtmp[e]);
    int pos = offs[d] + r.f.idx;
    r.f.idx = ei[e];  // replace rank with src
    __builtin_nontemporal_store(r.i4, &recs[pos]);
}

// ---- fused softmax + aggregation: one wave per dst node ----
// Unroll-8 with wave-uniform masked tail: 8 gathers always in flight, no
// serial remainder chain. recs has +8 slack; masked slots clamp src->self
// and select w->0 (select, not multiply: slack bytes may be poison).
__global__ __launch_bounds__(256) void k_agg(
    const float* __restrict__ asrc, const float* __restrict__ adst,
    const int* __restrict__ offs, const int* __restrict__ deg,
    const i32x4* __restrict__ recs, const half4_t* __restrict__ hh,
    float* __restrict__ out, int N)
{
    int wid = (blockIdx.x * 256 + threadIdx.x) >> 6;
    int lane = threadIdx.x & 63;
    if (wid >= N) return;
    const int i = wid;

    float4 b = *(const float4*)(adst + (size_t)i * H);
    float4 a0 = *(const float4*)(asrc + (size_t)i * H);
    float ws0 = __expf(lrelu(a0.x + b.x));
    float ws1 = __expf(lrelu(a0.y + b.y));
    float ws2 = __expf(lrelu(a0.z + b.z));
    float ws3 = __expf(lrelu(a0.w + b.w));

    const int beg = offs[i];
    const int dg = deg[i];

    // self-loop contribution
    float den0 = ws0, den1 = ws1, den2 = ws2, den3 = ws3;
    float acc0, acc1, acc2, acc3;
    {
        half4_t hv = hh[(size_t)i * D + lane];
        acc0 = ws0 * (float)hv[0];
        acc1 = ws1 * (float)hv[1];
        acc2 = ws2 * (float)hv[2];
        acc3 = ws3 * (float)hv[3];
    }

    for (int k = 0; k < dg; k += 8) {
        Rec r[8];
        half4_t hv[8];
        bool ok[8];
        #pragma unroll
        for (int j = 0; j < 8; j++) {
            r[j].i4 = recs[beg + k + j];          // may overread (slack/next dst)
            ok[j] = (k + j) < dg;                  // wave-uniform predicate
            int s = ok[j] ? r[j].f.idx : i;        // clamp to valid index
            hv[j] = hh[(size_t)s * D + lane];
        }
        #pragma unroll
        for (int j = 0; j < 8; j++) {
            float w0 = ok[j] ? (float)r[j].f.w[0] : 0.f;
            float w1 = ok[j] ? (float)r[j].f.w[1] : 0.f;
            float w2 = ok[j] ? (float)r[j].f.w[2] : 0.f;
            float w3 = ok[j] ? (float)r[j].f.w[3] : 0.f;
            den0 += w0; den1 += w1; den2 += w2; den3 += w3;
            acc0 += w0 * (float)hv[j][0];
            acc1 += w1 * (float)hv[j][1];
            acc2 += w2 * (float)hv[j][2];
            acc3 += w3 * (float)hv[j][3];
        }
    }

    out[(size_t)i * D + lane] =
        0.25f * (acc0 / den0 + acc1 / den1 + acc2 / den2 + acc3 / den3);
}

// BN stats: per-channel sum & sumsq (channel = idx & 63)
__global__ __launch_bounds__(256) void k_bn_stats(const float* __restrict__ out,
                                                  float* __restrict__ sums,
                                                  int total) {
    const int t = threadIdx.x;
    const int stride = gridDim.x * 256;
    float s = 0.f, sq = 0.f;
    for (int idx = blockIdx.x * 256 + t; idx < total; idx += stride) {
        float v = out[idx];
        s += v;
        sq += v * v;
    }
    __shared__ float ls[256], lq[256];
    ls[t] = s;
    lq[t] = sq;
    __syncthreads();
    if (t < 64) {
        s = ls[t] + ls[t + 64] + ls[t + 128] + ls[t + 192];
        sq = lq[t] + lq[t + 64] + lq[t + 128] + lq[t + 192];
        atomicAdd(&sums[t], s);
        atomicAdd(&sums[64 + t], sq);
    }
}

__global__ __launch_bounds__(256) void k_bn_apply(float* __restrict__ out,
                                                  const float* __restrict__ sums,
                                                  const float* __restrict__ gamma,
                                                  const float* __restrict__ beta,
                                                  int total, float invN) {
    int idx = blockIdx.x * 256 + threadIdx.x;
    if (idx >= total) return;
    int c = idx & 63;
    float mean = sums[c] * invN;
    float var = sums[64 + c] * invN - mean * mean;
    float y = gamma[c] * (out[idx] - mean) * rsqrtf(var + BN_EPS) + beta[c];
    out[idx] = fmaxf(y, 0.f);
}

extern "C" void kernel_launch(void* const* d_in, const int* in_sizes, int n_in,
                              void* d_out, int out_size, void* d_ws, size_t ws_size,
                              hipStream_t stream) {
    const float* x       = (const float*)d_in[0];
    const int*   ei      = (const int*)d_in[1];
    const float* W_lin   = (const float*)d_in[2];
    const float* b_lin   = (const float*)d_in[3];
    const float* prelu_w = (const float*)d_in[4];
    const float* W_gat   = (const float*)d_in[5];
    const float* att_src = (const float*)d_in[6];
    const float* att_dst = (const float*)d_in[7];
    // d_in[8] = gat_bias: constant per-channel shift cancelled exactly by BN
    // mean-subtraction -> skipped.
    const float* bn_gamma = (const float*)d_in[9];
    const float* bn_beta  = (const float*)d_in[10];
    float* out = (float*)d_out;

    const int N = in_sizes[0] / D;
    const int E = in_sizes[1] / 2;

    // workspace carve-up (all chunk sizes multiples of 16B)
    char* wp = (char*)d_ws;
    _Float16* hh = (_Float16*)wp;      wp += (size_t)N * D * H * sizeof(_Float16);
    float* asrc  = (float*)wp;          wp += (size_t)N * H * sizeof(float);
    float* adst  = (float*)wp;          wp += (size_t)N * H * sizeof(float);
    float* sums  = (float*)wp;          wp += 2 * D * sizeof(float);
    int* deg     = (int*)wp;            wp += (size_t)N * sizeof(int);
    int* offs    = (int*)wp;            wp += (size_t)N * sizeof(int);
    int* gcount  = (int*)wp;            wp += 4 * sizeof(int);
    _Float16* wlin_hi = (_Float16*)wp;  wp += 4096 * sizeof(_Float16);
    _Float16* wlin_lo = (_Float16*)wp;  wp += 4096 * sizeof(_Float16);
    _Float16* wgat_hi = (_Float16*)wp;  wp += 16384 * sizeof(_Float16);
    _Float16* wgat_lo = (_Float16*)wp;  wp += 16384 * sizeof(_Float16);
    i32x4* rtmp  = (i32x4*)wp;          wp += (size_t)E * sizeof(i32x4);
    i32x4* recs  = (i32x4*)wp;          wp += ((size_t)E + 8) * sizeof(i32x4);  // +8 slack for unroll-8 overread
    (void)ws_size; (void)n_in; (void)out_size;

    const int total = N * D;
    const int NB = (N + 255) / 256;

    hipLaunchKernelGGL(k_prep, dim3(80), dim3(256), 0, stream,
                       W_lin, W_gat, wlin_hi, wlin_lo, wgat_hi, wgat_lo);
    hipLaunchKernelGGL(k_node, dim3((N + 31) / 32), dim3(256), 0, stream,
                       x, wlin_hi, wlin_lo, b_lin, prelu_w, wgat_hi, wgat_lo,
                       att_src, att_dst, hh, asrc, adst, deg, sums, gcount, N);
    hipLaunchKernelGGL(k_hist_w, dim3((E + 255) / 256), dim3(256), 0, stream,
                       ei, deg, asrc, adst, rtmp, E);
    hipLaunchKernelGGL(k_offsets, dim3(NB), dim3(256), 0, stream,
                       deg, gcount, offs, N);
    hipLaunchKernelGGL(k_fill, dim3((E + 255) / 256), dim3(256), 0, stream,
                       ei, offs, rtmp, recs, E);
    hipLaunchKernelGGL(k_agg, dim3((N + 3) / 4), dim3(256), 0, stream,
                       asrc, adst, offs, deg, recs, (const half4_t*)hh, out, N);
    hipLaunchKernelGGL(k_bn_stats, dim3(1024), dim3(256), 0, stream,
                       out, sums, total);
    hipLaunchKernelGGL(k_bn_apply, dim3((total + 255) / 256), dim3(256), 0, stream,
                       out, sums, bn_gamma, bn_beta, total, 1.f / (float)N);
}

// Round 10
// 288.394 us; speedup vs baseline: 1.0102x; 1.0102x over previous
//
#include <hip/hip_runtime.h>
#include <hip/hip_fp16.h>

#define NEG_SLOPE 0.2f
#define BN_EPS 1e-5f

constexpr int D = 64;   // feature dim
constexpr int H = 4;    // heads

typedef _Float16 half4_t __attribute__((ext_vector_type(4)));
typedef _Float16 half8_t __attribute__((ext_vector_type(8)));
typedef float f32x4_t __attribute__((ext_vector_type(4)));
typedef int i32x4 __attribute__((ext_vector_type(4)));  // native vec for nontemporal builtins

// 16-B edge record: {src, pad, w[4]}; w = per-edge softmax numerators (4 heads)
union Rec {
    i32x4 i4;
    struct { int idx; int pad; half4_t w; } f;
};

#define MFMA16(a, b, c) __builtin_amdgcn_mfma_f32_16x16x32_f16(a, b, c, 0, 0, 0)

__device__ inline float lrelu(float v) { return (v >= 0.f) ? v : NEG_SLOPE * v; }

// load 8 consecutive fp32, split into fp16 hi + lo halves (hi+lo ~ fp32)
__device__ inline void split8(const float* p, bool ok, half8_t& hi, half8_t& lo) {
    float f[8];
    if (ok) {
        float4 a = *(const float4*)p;
        float4 b = *(const float4*)(p + 4);
        f[0] = a.x; f[1] = a.y; f[2] = a.z; f[3] = a.w;
        f[4] = b.x; f[5] = b.y; f[6] = b.z; f[7] = b.w;
    } else {
        #pragma unroll
        for (int j = 0; j < 8; j++) f[j] = 0.f;
    }
    #pragma unroll
    for (int j = 0; j < 8; j++) {
        _Float16 h = (_Float16)f[j];
        hi[j] = h;
        lo[j] = (_Float16)(f[j] - (float)h);
    }
}

// Fused MFMA node kernel (R4 form: weights split in-kernel, no k_prep):
// x1 = prelu(x @ W_lin^T + b_lin); h = x1 @ W_gat^T (split-fp16 MFMA ~ fp32);
// h stored fp16 layout [n][d][head]; attention dots from accumulators.
// Also zeroes deg slice / sums / gcount.
__global__ __launch_bounds__(256) void k_node(
    const float* __restrict__ x,
    const float* __restrict__ W_lin, const float* __restrict__ b_lin,
    const float* __restrict__ prelu_w, const float* __restrict__ W_gat,
    const float* __restrict__ att_src, const float* __restrict__ att_dst,
    _Float16* __restrict__ hh, float* __restrict__ asrc_ws,
    float* __restrict__ adst_ws, int* __restrict__ deg,
    float* __restrict__ sums, int* __restrict__ gcount, int N)
{
    __shared__ _Float16 h_lds[32 * 256];   // 16 KB, [m][d*4+head]
    __shared__ _Float16 x1hi[32 * 72];     // 4.5 KB, row-padded (72 halves=144B)
    __shared__ _Float16 x1lo[32 * 72];

    const int t = threadIdx.x;
    const int w = t >> 6;    // wave id == head
    const int l = t & 63;
    const int li = l & 15;
    const int lq = l >> 4;
    const int base = blockIdx.x * 32;
    const int nvalid = min(32, N - base);

    // fused init: zero this block's deg slice; block 0 zeroes sums + gcount
    if (t < nvalid) deg[base + t] = 0;
    if (blockIdx.x == 0) {
        if (t < 2 * D) sums[t] = 0.f;
        if (t == 0) *gcount = 0;
    }

    // ---- stage A: MFMA x @ W_lin^T for cols 16w..16w+15 ----
    f32x4_t accA[2] = {};
    half8_t blh[2], bll[2];
    {
        const int n = 16 * w + li;
        #pragma unroll
        for (int ks = 0; ks < 2; ks++)
            split8(W_lin + n * 64 + 32 * ks + 8 * lq, true, blh[ks], bll[ks]);
    }
    #pragma unroll
    for (int mt = 0; mt < 2; mt++) {
        const int row = base + 16 * mt + li;
        const bool ok = row < N;
        #pragma unroll
        for (int ks = 0; ks < 2; ks++) {
            half8_t ah, al;
            split8(x + (size_t)row * 64 + 32 * ks + 8 * lq, ok, ah, al);
            accA[mt] = MFMA16(ah, blh[ks], accA[mt]);
            accA[mt] = MFMA16(al, blh[ks], accA[mt]);
            accA[mt] = MFMA16(ah, bll[ks], accA[mt]);
        }
    }
    // epilogue A: +bias, prelu, split to fp16 hi/lo in LDS
    {
        const int n = 16 * w + li;
        const float bl = b_lin[n];
        const float pw = prelu_w[n];
        #pragma unroll
        for (int mt = 0; mt < 2; mt++) {
            #pragma unroll
            for (int r = 0; r < 4; r++) {
                const int m = 16 * mt + lq * 4 + r;
                float v = accA[mt][r] + bl;
                v = (v >= 0.f) ? v : pw * v;
                _Float16 hi = (_Float16)v;
                x1hi[m * 72 + n] = hi;
                x1lo[m * 72 + n] = (_Float16)(v - (float)hi);
            }
        }
    }
    __syncthreads();

    // ---- stage B: MFMA x1 @ W_gat^T for cols 64w..64w+63 ----
    half8_t xah[2][2], xal[2][2];
    #pragma unroll
    for (int mt = 0; mt < 2; mt++) {
        #pragma unroll
        for (int ks = 0; ks < 2; ks++) {
            const int off = (16 * mt + li) * 72 + 32 * ks + 8 * lq;
            xah[mt][ks] = *(const half8_t*)(&x1hi[off]);
            xal[mt][ks] = *(const half8_t*)(&x1lo[off]);
        }
    }
    f32x4_t accB[2][4] = {};
    #pragma unroll
    for (int nt = 0; nt < 4; nt++) {
        half8_t wh[2], wl[2];
        const int c = 64 * w + 16 * nt + li;
        #pragma unroll
        for (int ks = 0; ks < 2; ks++)
            split8(W_gat + (size_t)c * 64 + 32 * ks + 8 * lq, true, wh[ks], wl[ks]);
        #pragma unroll
        for (int mt = 0; mt < 2; mt++) {
            #pragma unroll
            for (int ks = 0; ks < 2; ks++) {
                accB[mt][nt] = MFMA16(xah[mt][ks], wh[ks], accB[mt][nt]);
                accB[mt][nt] = MFMA16(xal[mt][ks], wh[ks], accB[mt][nt]);
                accB[mt][nt] = MFMA16(xah[mt][ks], wl[ks], accB[mt][nt]);
            }
        }
    }

    // ---- attention dots from registers: a[n][w] = sum_d h[n][w][d]*att[w][d]
    {
        float asv[4], adv[4];
        #pragma unroll
        for (int nt = 0; nt < 4; nt++) {
            const int c = 64 * w + 16 * nt + li;
            asv[nt] = att_src[c];
            adv[nt] = att_dst[c];
        }
        #pragma unroll
        for (int mt = 0; mt < 2; mt++) {
            #pragma unroll
            for (int r = 0; r < 4; r++) {
                float s = 0.f, dsum = 0.f;
                #pragma unroll
                for (int nt = 0; nt < 4; nt++) {
                    s += accB[mt][nt][r] * asv[nt];
                    dsum += accB[mt][nt][r] * adv[nt];
                }
                #pragma unroll
                for (int off = 1; off < 16; off <<= 1) {
                    s += __shfl_xor(s, off, 64);
                    dsum += __shfl_xor(dsum, off, 64);
                }
                if (li == 0) {
                    const int m = 16 * mt + lq * 4 + r;
                    if (m < nvalid) {
                        asrc_ws[(size_t)(base + m) * H + w] = s;
                        adst_ws[(size_t)(base + m) * H + w] = dsum;
                    }
                }
            }
        }
    }

    // ---- h -> LDS in [m][d*4+head] layout, then coalesced global write ----
    #pragma unroll
    for (int mt = 0; mt < 2; mt++) {
        #pragma unroll
        for (int nt = 0; nt < 4; nt++) {
            #pragma unroll
            for (int r = 0; r < 4; r++) {
                const int m = 16 * mt + lq * 4 + r;
                const int d = 16 * nt + li;
                h_lds[m * 256 + d * 4 + w] = (_Float16)accB[mt][nt][r];
            }
        }
    }
    __syncthreads();
    {
        const int chunks = nvalid * 32;  // 8 halves (16B) per chunk
        const uint4* src = (const uint4*)h_lds;
        uint4* dst = (uint4*)(hh + (size_t)base * 256);
        for (int i = t; i < chunks; i += 256) dst[i] = src[i];
    }
}

// ---- hist + rank (edge-order, coalesced 4-B NT store) ----
// atomicAdd's return IS the edge's rank within its dst.
__global__ __launch_bounds__(256) void k_hist(const int* __restrict__ ei,
                                              int* __restrict__ deg,
                                              int* __restrict__ rank,
                                              int E) {
    int e = blockIdx.x * 256 + threadIdx.x;
    if (e >= E) return;
    int d = ei[E + e];
    int r = atomicAdd(&deg[d], 1);
    __builtin_nontemporal_store(r, &rank[e]);
}

// single-kernel offsets: per-block exclusive scan + one atomicAdd for the
// block's base (bucket order across blocks is irrelevant — only disjointness
// and per-dst contiguity matter).
__global__ __launch_bounds__(256) void k_offsets(const int* __restrict__ deg,
                                                 int* __restrict__ gcount,
                                                 int* __restrict__ offs, int N) {
    __shared__ int sm[256];
    __shared__ int sbase;
    int t = threadIdx.x;
    int idx = blockIdx.x * 256 + t;
    int v = (idx < N) ? deg[idx] : 0;
    sm[t] = v;
    __syncthreads();
    for (int off = 1; off < 256; off <<= 1) {
        int w = (t >= off) ? sm[t - off] : 0;
        __syncthreads();
        sm[t] += w;
        __syncthreads();
    }
    if (t == 255) sbase = atomicAdd(gcount, sm[255]);
    __syncthreads();
    if (idx < N) offs[idx] = sbase + sm[t] - v;  // exclusive within block + base
}

// atomic-free permute-scatter: pos = offs[dst] + rank. Computes w from the
// L2-resident asrc/adst tables (800 KB each). One random 16-B NT store/edge.
__global__ __launch_bounds__(256) void k_fill(const int* __restrict__ ei,
                                              const int* __restrict__ offs,
                                              const int* __restrict__ rank,
                                              const float* __restrict__ asrc,
                                              const float* __restrict__ adst,
                                              i32x4* __restrict__ recs, int E) {
    int e = blockIdx.x * 256 + threadIdx.x;
    if (e >= E) return;
    int s = ei[e];
    int d = ei[E + e];
    int r0 = __builtin_nontemporal_load(&rank[e]);
    int pos = offs[d] + r0;
    float4 a = *(const float4*)(asrc + (size_t)s * H);
    float4 b = *(const float4*)(adst + (size_t)d * H);
    Rec r;
    r.f.idx = s;
    r.f.pad = 0;
    r.f.w[0] = (_Float16)__expf(lrelu(a.x + b.x));
    r.f.w[1] = (_Float16)__expf(lrelu(a.y + b.y));
    r.f.w[2] = (_Float16)__expf(lrelu(a.z + b.z));
    r.f.w[3] = (_Float16)__expf(lrelu(a.w + b.w));
    __builtin_nontemporal_store(r.i4, &recs[pos]);
}

// ---- fused softmax + aggregation: one wave per dst node (R5 best form) ----
// Main loop = clean unroll-4; tail = ONE masked group of 4 (wave-uniform
// selects; recs has +4 slack; masked slots clamp src->self, w->0).
__global__ __launch_bounds__(256) void k_agg(
    const float* __restrict__ asrc, const float* __restrict__ adst,
    const int* __restrict__ offs, const int* __restrict__ deg,
    const i32x4* __restrict__ recs, const half4_t* __restrict__ hh,
    float* __restrict__ out, int N)
{
    int wid = (blockIdx.x * 256 + threadIdx.x) >> 6;
    int lane = threadIdx.x & 63;
    if (wid >= N) return;
    const int i = wid;

    float4 b = *(const float4*)(adst + (size_t)i * H);
    float4 a0 = *(const float4*)(asrc + (size_t)i * H);
    float ws0 = __expf(lrelu(a0.x + b.x));
    float ws1 = __expf(lrelu(a0.y + b.y));
    float ws2 = __expf(lrelu(a0.z + b.z));
    float ws3 = __expf(lrelu(a0.w + b.w));

    const int beg = offs[i];
    const int dg = deg[i];

    // self-loop contribution
    float den0 = ws0, den1 = ws1, den2 = ws2, den3 = ws3;
    float acc0, acc1, acc2, acc3;
    {
        half4_t hv = hh[(size_t)i * D + lane];
        acc0 = ws0 * (float)hv[0];
        acc1 = ws1 * (float)hv[1];
        acc2 = ws2 * (float)hv[2];
        acc3 = ws3 * (float)hv[3];
    }
    int k = 0;
    for (; k + 4 <= dg; k += 4) {
        Rec r0, r1, r2, r3;
        r0.i4 = recs[beg + k];
        r1.i4 = recs[beg + k + 1];
        r2.i4 = recs[beg + k + 2];
        r3.i4 = recs[beg + k + 3];
        half4_t h0 = hh[(size_t)r0.f.idx * D + lane];
        half4_t h1 = hh[(size_t)r1.f.idx * D + lane];
        half4_t h2 = hh[(size_t)r2.f.idx * D + lane];
        half4_t h3 = hh[(size_t)r3.f.idx * D + lane];
        float w00 = (float)r0.f.w[0], w01 = (float)r0.f.w[1],
              w02 = (float)r0.f.w[2], w03 = (float)r0.f.w[3];
        float w10 = (float)r1.f.w[0], w11 = (float)r1.f.w[1],
              w12 = (float)r1.f.w[2], w13 = (float)r1.f.w[3];
        float w20 = (float)r2.f.w[0], w21 = (float)r2.f.w[1],
              w22 = (float)r2.f.w[2], w23 = (float)r2.f.w[3];
        float w30 = (float)r3.f.w[0], w31 = (float)r3.f.w[1],
              w32 = (float)r3.f.w[2], w33 = (float)r3.f.w[3];
        den0 += w00 + w10 + w20 + w30;
        den1 += w01 + w11 + w21 + w31;
        den2 += w02 + w12 + w22 + w32;
        den3 += w03 + w13 + w23 + w33;
        acc0 += w00 * (float)h0[0] + w10 * (float)h1[0] +
                w20 * (float)h2[0] + w30 * (float)h3[0];
        acc1 += w01 * (float)h0[1] + w11 * (float)h1[1] +
                w21 * (float)h2[1] + w31 * (float)h3[1];
        acc2 += w02 * (float)h0[2] + w12 * (float)h1[2] +
                w22 * (float)h2[2] + w32 * (float)h3[2];
        acc3 += w03 * (float)h0[3] + w13 * (float)h1[3] +
                w23 * (float)h2[3] + w33 * (float)h3[3];
    }
    if (k < dg) {
        // single masked tail group (1-3 valid slots)
        Rec r[4];
        half4_t hv[4];
        bool ok[4];
        #pragma unroll
        for (int j = 0; j < 4; j++) {
            r[j].i4 = recs[beg + k + j];       // may overread into slack
            ok[j] = (k + j) < dg;
            int s = ok[j] ? r[j].f.idx : i;
            hv[j] = hh[(size_t)s * D + lane];
        }
        #pragma unroll
        for (int j = 0; j < 4; j++) {
            float w0 = ok[j] ? (float)r[j].f.w[0] : 0.f;
            float w1 = ok[j] ? (float)r[j].f.w[1] : 0.f;
            float w2 = ok[j] ? (float)r[j].f.w[2] : 0.f;
            float w3 = ok[j] ? (float)r[j].f.w[3] : 0.f;
            den0 += w0; den1 += w1; den2 += w2; den3 += w3;
            acc0 += w0 * (float)hv[j][0];
            acc1 += w1 * (float)hv[j][1];
            acc2 += w2 * (float)hv[j][2];
            acc3 += w3 * (float)hv[j][3];
        }
    }

    out[(size_t)i * D + lane] =
        0.25f * (acc0 / den0 + acc1 / den1 + acc2 / den2 + acc3 / den3);
}

// BN stats: per-channel sum & sumsq (channel = idx & 63)
__global__ __launch_bounds__(256) void k_bn_stats(const float* __restrict__ out,
                                                  float* __restrict__ sums,
                                                  int total) {
    const int t = threadIdx.x;
    const int stride = gridDim.x * 256;
    float s = 0.f, sq = 0.f;
    for (int idx = blockIdx.x * 256 + t; idx < total; idx += stride) {
        float v = out[idx];
        s += v;
        sq += v * v;
    }
    __shared__ float ls[256], lq[256];
    ls[t] = s;
    lq[t] = sq;
    __syncthreads();
    if (t < 64) {
        s = ls[t] + ls[t + 64] + ls[t + 128] + ls[t + 192];
        sq = lq[t] + lq[t + 64] + lq[t + 128] + lq[t + 192];
        atomicAdd(&sums[t], s);
        atomicAdd(&sums[64 + t], sq);
    }
}

__global__ __launch_bounds__(256) void k_bn_apply(float* __restrict__ out,
                                                  const float* __restrict__ sums,
                                                  const float* __restrict__ gamma,
                                                  const float* __restrict__ beta,
                                                  int total, float invN) {
    int idx = blockIdx.x * 256 + threadIdx.x;
    if (idx >= total) return;
    int c = idx & 63;
    float mean = sums[c] * invN;
    float var = sums[64 + c] * invN - mean * mean;
    float y = gamma[c] * (out[idx] - mean) * rsqrtf(var + BN_EPS) + beta[c];
    out[idx] = fmaxf(y, 0.f);
}

extern "C" void kernel_launch(void* const* d_in, const int* in_sizes, int n_in,
                              void* d_out, int out_size, void* d_ws, size_t ws_size,
                              hipStream_t stream) {
    const float* x       = (const float*)d_in[0];
    const int*   ei      = (const int*)d_in[1];
    const float* W_lin   = (const float*)d_in[2];
    const float* b_lin   = (const float*)d_in[3];
    const float* prelu_w = (const float*)d_in[4];
    const float* W_gat   = (const float*)d_in[5];
    const float* att_src = (const float*)d_in[6];
    const float* att_dst = (const float*)d_in[7];
    // d_in[8] = gat_bias: constant per-channel shift cancelled exactly by BN
    // mean-subtraction -> skipped.
    const float* bn_gamma = (const float*)d_in[9];
    const float* bn_beta  = (const float*)d_in[10];
    float* out = (float*)d_out;

    const int N = in_sizes[0] / D;
    const int E = in_sizes[1] / 2;

    // workspace carve-up (all chunk sizes multiples of 16B)
    char* wp = (char*)d_ws;
    _Float16* hh = (_Float16*)wp;      wp += (size_t)N * D * H * sizeof(_Float16);
    float* asrc  = (float*)wp;          wp += (size_t)N * H * sizeof(float);
    float* adst  = (float*)wp;          wp += (size_t)N * H * sizeof(float);
    float* sums  = (float*)wp;          wp += 2 * D * sizeof(float);
    int* deg     = (int*)wp;            wp += (size_t)N * sizeof(int);
    int* offs    = (int*)wp;            wp += (size_t)N * sizeof(int);
    int* gcount  = (int*)wp;            wp += 4 * sizeof(int);
    int* rank    = (int*)wp;            wp += (size_t)E * sizeof(int);
    i32x4* recs  = (i32x4*)wp;          wp += ((size_t)E + 4) * sizeof(i32x4);  // +4 slack for masked tail
    (void)ws_size; (void)n_in; (void)out_size;

    const int total = N * D;
    const int NB = (N + 255) / 256;

    hipLaunchKernelGGL(k_node, dim3((N + 31) / 32), dim3(256), 0, stream,
                       x, W_lin, b_lin, prelu_w, W_gat, att_src, att_dst,
                       hh, asrc, adst, deg, sums, gcount, N);
    hipLaunchKernelGGL(k_hist, dim3((E + 255) / 256), dim3(256), 0, stream,
                       ei, deg, rank, E);
    hipLaunchKernelGGL(k_offsets, dim3(NB), dim3(256), 0, stream,
                       deg, gcount, offs, N);
    hipLaunchKernelGGL(k_fill, dim3((E + 255) / 256), dim3(256), 0, stream,
                       ei, offs, rank, asrc, adst, recs, E);
    hipLaunchKernelGGL(k_agg, dim3((N + 3) / 4), dim3(256), 0, stream,
                       asrc, adst, offs, deg, recs, (const half4_t*)hh, out, N);
    hipLaunchKernelGGL(k_bn_stats, dim3(1024), dim3(256), 0, stream,
                       out, sums, total);
    hipLaunchKernelGGL(k_bn_apply, dim3((total + 255) / 256), dim3(256), 0, stream,
                       out, sums, bn_gamma, bn_beta, total, 1.f / (float)N);
}

// Round 11
// 285.518 us; speedup vs baseline: 1.0204x; 1.0101x over previous
//
#include <hip/hip_runtime.h>
#include <hip/hip_fp16.h>

#define NEG_SLOPE 0.2f
#define BN_EPS 1e-5f

constexpr int D = 64;   // feature dim
constexpr int H = 4;    // heads

typedef _Float16 half4_t __attribute__((ext_vector_type(4)));
typedef _Float16 half8_t __attribute__((ext_vector_type(8)));
typedef float f32x4_t __attribute__((ext_vector_type(4)));
typedef int i32x4 __attribute__((ext_vector_type(4)));  // native vec for nontemporal builtins

// 16-B edge record: {src, pad, w[4]}; w = per-edge softmax numerators (4 heads)
union Rec {
    i32x4 i4;
    struct { int idx; int pad; half4_t w; } f;
};

#define MFMA16(a, b, c) __builtin_amdgcn_mfma_f32_16x16x32_f16(a, b, c, 0, 0, 0)

__device__ inline float lrelu(float v) { return (v >= 0.f) ? v : NEG_SLOPE * v; }

// load 8 consecutive fp32, split into fp16 hi + lo halves (hi+lo ~ fp32)
__device__ inline void split8(const float* p, bool ok, half8_t& hi, half8_t& lo) {
    float f[8];
    if (ok) {
        float4 a = *(const float4*)p;
        float4 b = *(const float4*)(p + 4);
        f[0] = a.x; f[1] = a.y; f[2] = a.z; f[3] = a.w;
        f[4] = b.x; f[5] = b.y; f[6] = b.z; f[7] = b.w;
    } else {
        #pragma unroll
        for (int j = 0; j < 8; j++) f[j] = 0.f;
    }
    #pragma unroll
    for (int j = 0; j < 8; j++) {
        _Float16 h = (_Float16)f[j];
        hi[j] = h;
        lo[j] = (_Float16)(f[j] - (float)h);
    }
}

// Fused MFMA node kernel: x1 = prelu(x @ W_lin^T + b_lin); h = x1 @ W_gat^T
// (split-fp16 MFMA ~ fp32); h stored fp16 layout [n][d][head]; attention dots
// from accumulators. Also zeroes deg8 slices / sums / gcount.
__global__ __launch_bounds__(256) void k_node(
    const float* __restrict__ x,
    const float* __restrict__ W_lin, const float* __restrict__ b_lin,
    const float* __restrict__ prelu_w, const float* __restrict__ W_gat,
    const float* __restrict__ att_src, const float* __restrict__ att_dst,
    _Float16* __restrict__ hh, float* __restrict__ asrc_ws,
    float* __restrict__ adst_ws, int* __restrict__ deg8,
    float* __restrict__ sums, int* __restrict__ gcount, int N)
{
    __shared__ _Float16 h_lds[32 * 256];   // 16 KB, [m][d*4+head]
    __shared__ _Float16 x1hi[32 * 72];     // 4.5 KB, row-padded (72 halves=144B)
    __shared__ _Float16 x1lo[32 * 72];

    const int t = threadIdx.x;
    const int w = t >> 6;    // wave id == head
    const int l = t & 63;
    const int li = l & 15;
    const int lq = l >> 4;
    const int base = blockIdx.x * 32;
    const int nvalid = min(32, N - base);

    // fused init: grid-stride zero of deg8 (8*N ints); block 0: sums + gcount
    {
        const int stride = gridDim.x * 256;
        for (int i = blockIdx.x * 256 + t; i < 8 * N; i += stride) deg8[i] = 0;
    }
    if (blockIdx.x == 0) {
        if (t < 2 * D) sums[t] = 0.f;
        if (t == 0) *gcount = 0;
    }

    // ---- stage A: MFMA x @ W_lin^T for cols 16w..16w+15 ----
    f32x4_t accA[2] = {};
    half8_t blh[2], bll[2];
    {
        const int n = 16 * w + li;
        #pragma unroll
        for (int ks = 0; ks < 2; ks++)
            split8(W_lin + n * 64 + 32 * ks + 8 * lq, true, blh[ks], bll[ks]);
    }
    #pragma unroll
    for (int mt = 0; mt < 2; mt++) {
        const int row = base + 16 * mt + li;
        const bool ok = row < N;
        #pragma unroll
        for (int ks = 0; ks < 2; ks++) {
            half8_t ah, al;
            split8(x + (size_t)row * 64 + 32 * ks + 8 * lq, ok, ah, al);
            accA[mt] = MFMA16(ah, blh[ks], accA[mt]);
            accA[mt] = MFMA16(al, blh[ks], accA[mt]);
            accA[mt] = MFMA16(ah, bll[ks], accA[mt]);
        }
    }
    // epilogue A: +bias, prelu, split to fp16 hi/lo in LDS
    {
        const int n = 16 * w + li;
        const float bl = b_lin[n];
        const float pw = prelu_w[n];
        #pragma unroll
        for (int mt = 0; mt < 2; mt++) {
            #pragma unroll
            for (int r = 0; r < 4; r++) {
                const int m = 16 * mt + lq * 4 + r;
                float v = accA[mt][r] + bl;
                v = (v >= 0.f) ? v : pw * v;
                _Float16 hi = (_Float16)v;
                x1hi[m * 72 + n] = hi;
                x1lo[m * 72 + n] = (_Float16)(v - (float)hi);
            }
        }
    }
    __syncthreads();

    // ---- stage B: MFMA x1 @ W_gat^T for cols 64w..64w+63 ----
    half8_t xah[2][2], xal[2][2];
    #pragma unroll
    for (int mt = 0; mt < 2; mt++) {
        #pragma unroll
        for (int ks = 0; ks < 2; ks++) {
            const int off = (16 * mt + li) * 72 + 32 * ks + 8 * lq;
            xah[mt][ks] = *(const half8_t*)(&x1hi[off]);
            xal[mt][ks] = *(const half8_t*)(&x1lo[off]);
        }
    }
    f32x4_t accB[2][4] = {};
    #pragma unroll
    for (int nt = 0; nt < 4; nt++) {
        half8_t wh[2], wl[2];
        const int c = 64 * w + 16 * nt + li;
        #pragma unroll
        for (int ks = 0; ks < 2; ks++)
            split8(W_gat + (size_t)c * 64 + 32 * ks + 8 * lq, true, wh[ks], wl[ks]);
        #pragma unroll
        for (int mt = 0; mt < 2; mt++) {
            #pragma unroll
            for (int ks = 0; ks < 2; ks++) {
                accB[mt][nt] = MFMA16(xah[mt][ks], wh[ks], accB[mt][nt]);
                accB[mt][nt] = MFMA16(xal[mt][ks], wh[ks], accB[mt][nt]);
                accB[mt][nt] = MFMA16(xah[mt][ks], wl[ks], accB[mt][nt]);
            }
        }
    }

    // ---- attention dots from registers: a[n][w] = sum_d h[n][w][d]*att[w][d]
    {
        float asv[4], adv[4];
        #pragma unroll
        for (int nt = 0; nt < 4; nt++) {
            const int c = 64 * w + 16 * nt + li;
            asv[nt] = att_src[c];
            adv[nt] = att_dst[c];
        }
        #pragma unroll
        for (int mt = 0; mt < 2; mt++) {
            #pragma unroll
            for (int r = 0; r < 4; r++) {
                float s = 0.f, dsum = 0.f;
                #pragma unroll
                for (int nt = 0; nt < 4; nt++) {
                    s += accB[mt][nt][r] * asv[nt];
                    dsum += accB[mt][nt][r] * adv[nt];
                }
                #pragma unroll
                for (int off = 1; off < 16; off <<= 1) {
                    s += __shfl_xor(s, off, 64);
                    dsum += __shfl_xor(dsum, off, 64);
                }
                if (li == 0) {
                    const int m = 16 * mt + lq * 4 + r;
                    if (m < nvalid) {
                        asrc_ws[(size_t)(base + m) * H + w] = s;
                        adst_ws[(size_t)(base + m) * H + w] = dsum;
                    }
                }
            }
        }
    }

    // ---- h -> LDS in [m][d*4+head] layout, then coalesced global write ----
    #pragma unroll
    for (int mt = 0; mt < 2; mt++) {
        #pragma unroll
        for (int nt = 0; nt < 4; nt++) {
            #pragma unroll
            for (int r = 0; r < 4; r++) {
                const int m = 16 * mt + lq * 4 + r;
                const int d = 16 * nt + li;
                h_lds[m * 256 + d * 4 + w] = (_Float16)accB[mt][nt][r];
            }
        }
    }
    __syncthreads();
    {
        const int chunks = nvalid * 32;  // 8 halves (16B) per chunk
        const uint4* src = (const uint4*)h_lds;
        uint4* dst = (uint4*)(hh + (size_t)base * 256);
        for (int i = t; i < chunks; i += 256) dst[i] = src[i];
    }
}

// ---- hist + rank, XCD-privatized ----
// p = (e>>8)&7 tracks the round-robin block->XCD mapping, so each XCD's
// atomics hit only its own deg8 slice -> no cross-XCD line ping-pong.
// atomicAdd's return IS the edge's rank within (p, dst).
__global__ __launch_bounds__(256) void k_hist(const int* __restrict__ ei,
                                              int* __restrict__ deg8,
                                              int* __restrict__ rank,
                                              int N, int E) {
    int e = blockIdx.x * 256 + threadIdx.x;
    if (e >= E) return;
    int d = ei[E + e];
    int p = (e >> 8) & 7;
    int r = atomicAdd(&deg8[p * N + d], 1);
    __builtin_nontemporal_store(r, &rank[e]);
}

// offsets: fold the 8 slices (exclusive prefix over p -> pref8, total -> deg),
// then per-block exclusive scan + one atomicAdd for the block's recs base.
__global__ __launch_bounds__(256) void k_offsets(const int* __restrict__ deg8,
                                                 int* __restrict__ pref8,
                                                 int* __restrict__ deg,
                                                 int* __restrict__ gcount,
                                                 int* __restrict__ offs, int N) {
    __shared__ int sm[256];
    __shared__ int sbase;
    int t = threadIdx.x;
    int idx = blockIdx.x * 256 + t;
    int v = 0;
    if (idx < N) {
        #pragma unroll
        for (int p = 0; p < 8; p++) {
            int c = deg8[p * N + idx];
            pref8[p * N + idx] = v;
            v += c;
        }
        deg[idx] = v;
    }
    sm[t] = v;
    __syncthreads();
    for (int off = 1; off < 256; off <<= 1) {
        int w = (t >= off) ? sm[t - off] : 0;
        __syncthreads();
        sm[t] += w;
        __syncthreads();
    }
    if (t == 255) sbase = atomicAdd(gcount, sm[255]);
    __syncthreads();
    if (idx < N) offs[idx] = sbase + sm[t] - v;  // exclusive within block + base
}

// atomic-free permute-scatter: pos = offs[dst] + pref8[p][dst] + rank.
// Computes w from the L2-resident asrc/adst tables. Plain 16-B store (L2
// coalescing of the 4 records per line beats NT here — measured R5 vs R8).
__global__ __launch_bounds__(256) void k_fill(const int* __restrict__ ei,
                                              const int* __restrict__ offs,
                                              const int* __restrict__ pref8,
                                              const int* __restrict__ rank,
                                              const float* __restrict__ asrc,
                                              const float* __restrict__ adst,
                                              i32x4* __restrict__ recs,
                                              int N, int E) {
    int e = blockIdx.x * 256 + threadIdx.x;
    if (e >= E) return;
    int s = ei[e];
    int d = ei[E + e];
    int p = (e >> 8) & 7;
    int r0 = __builtin_nontemporal_load(&rank[e]);
    int pos = offs[d] + pref8[p * N + d] + r0;
    float4 a = *(const float4*)(asrc + (size_t)s * H);
    float4 b = *(const float4*)(adst + (size_t)d * H);
    Rec r;
    r.f.idx = s;
    r.f.pad = 0;
    r.f.w[0] = (_Float16)__expf(lrelu(a.x + b.x));
    r.f.w[1] = (_Float16)__expf(lrelu(a.y + b.y));
    r.f.w[2] = (_Float16)__expf(lrelu(a.z + b.z));
    r.f.w[3] = (_Float16)__expf(lrelu(a.w + b.w));
    recs[pos] = r.i4;
}

// ---- fused softmax + aggregation: one wave per dst node (R5 best form) ----
__global__ __launch_bounds__(256) void k_agg(
    const float* __restrict__ asrc, const float* __restrict__ adst,
    const int* __restrict__ offs, const int* __restrict__ deg,
    const i32x4* __restrict__ recs, const half4_t* __restrict__ hh,
    float* __restrict__ out, int N)
{
    int wid = (blockIdx.x * 256 + threadIdx.x) >> 6;
    int lane = threadIdx.x & 63;
    if (wid >= N) return;
    const int i = wid;

    float4 b = *(const float4*)(adst + (size_t)i * H);
    float4 a0 = *(const float4*)(asrc + (size_t)i * H);
    float ws0 = __expf(lrelu(a0.x + b.x));
    float ws1 = __expf(lrelu(a0.y + b.y));
    float ws2 = __expf(lrelu(a0.z + b.z));
    float ws3 = __expf(lrelu(a0.w + b.w));

    const int beg = offs[i];
    const int dg = deg[i];

    // self-loop contribution
    float den0 = ws0, den1 = ws1, den2 = ws2, den3 = ws3;
    float acc0, acc1, acc2, acc3;
    {
        half4_t hv = hh[(size_t)i * D + lane];
        acc0 = ws0 * (float)hv[0];
        acc1 = ws1 * (float)hv[1];
        acc2 = ws2 * (float)hv[2];
        acc3 = ws3 * (float)hv[3];
    }
    int k = 0;
    for (; k + 4 <= dg; k += 4) {
        Rec r0, r1, r2, r3;
        r0.i4 = recs[beg + k];
        r1.i4 = recs[beg + k + 1];
        r2.i4 = recs[beg + k + 2];
        r3.i4 = recs[beg + k + 3];
        half4_t h0 = hh[(size_t)r0.f.idx * D + lane];
        half4_t h1 = hh[(size_t)r1.f.idx * D + lane];
        half4_t h2 = hh[(size_t)r2.f.idx * D + lane];
        half4_t h3 = hh[(size_t)r3.f.idx * D + lane];
        float w00 = (float)r0.f.w[0], w01 = (float)r0.f.w[1],
              w02 = (float)r0.f.w[2], w03 = (float)r0.f.w[3];
        float w10 = (float)r1.f.w[0], w11 = (float)r1.f.w[1],
              w12 = (float)r1.f.w[2], w13 = (float)r1.f.w[3];
        float w20 = (float)r2.f.w[0], w21 = (float)r2.f.w[1],
              w22 = (float)r2.f.w[2], w23 = (float)r2.f.w[3];
        float w30 = (float)r3.f.w[0], w31 = (float)r3.f.w[1],
              w32 = (float)r3.f.w[2], w33 = (float)r3.f.w[3];
        den0 += w00 + w10 + w20 + w30;
        den1 += w01 + w11 + w21 + w31;
        den2 += w02 + w12 + w22 + w32;
        den3 += w03 + w13 + w23 + w33;
        acc0 += w00 * (float)h0[0] + w10 * (float)h1[0] +
                w20 * (float)h2[0] + w30 * (float)h3[0];
        acc1 += w01 * (float)h0[1] + w11 * (float)h1[1] +
                w21 * (float)h2[1] + w31 * (float)h3[1];
        acc2 += w02 * (float)h0[2] + w12 * (float)h1[2] +
                w22 * (float)h2[2] + w32 * (float)h3[2];
        acc3 += w03 * (float)h0[3] + w13 * (float)h1[3] +
                w23 * (float)h2[3] + w33 * (float)h3[3];
    }
    for (; k < dg; k++) {
        Rec r;
        r.i4 = recs[beg + k];
        half4_t hv = hh[(size_t)r.f.idx * D + lane];
        float w0 = (float)r.f.w[0], w1 = (float)r.f.w[1];
        float w2 = (float)r.f.w[2], w3 = (float)r.f.w[3];
        den0 += w0; den1 += w1; den2 += w2; den3 += w3;
        acc0 += w0 * (float)hv[0];
        acc1 += w1 * (float)hv[1];
        acc2 += w2 * (float)hv[2];
        acc3 += w3 * (float)hv[3];
    }

    out[(size_t)i * D + lane] =
        0.25f * (acc0 / den0 + acc1 / den1 + acc2 / den2 + acc3 / den3);
}

// BN stats: per-channel sum & sumsq (channel = idx & 63)
__global__ __launch_bounds__(256) void k_bn_stats(const float* __restrict__ out,
                                                  float* __restrict__ sums,
                                                  int total) {
    const int t = threadIdx.x;
    const int stride = gridDim.x * 256;
    float s = 0.f, sq = 0.f;
    for (int idx = blockIdx.x * 256 + t; idx < total; idx += stride) {
        float v = out[idx];
        s += v;
        sq += v * v;
    }
    __shared__ float ls[256], lq[256];
    ls[t] = s;
    lq[t] = sq;
    __syncthreads();
    if (t < 64) {
        s = ls[t] + ls[t + 64] + ls[t + 128] + ls[t + 192];
        sq = lq[t] + lq[t + 64] + lq[t + 128] + lq[t + 192];
        atomicAdd(&sums[t], s);
        atomicAdd(&sums[64 + t], sq);
    }
}

__global__ __launch_bounds__(256) void k_bn_apply(float* __restrict__ out,
                                                  const float* __restrict__ sums,
                                                  const float* __restrict__ gamma,
                                                  const float* __restrict__ beta,
                                                  int total, float invN) {
    int idx = blockIdx.x * 256 + threadIdx.x;
    if (idx >= total) return;
    int c = idx & 63;
    float mean = sums[c] * invN;
    float var = sums[64 + c] * invN - mean * mean;
    float y = gamma[c] * (out[idx] - mean) * rsqrtf(var + BN_EPS) + beta[c];
    out[idx] = fmaxf(y, 0.f);
}

extern "C" void kernel_launch(void* const* d_in, const int* in_sizes, int n_in,
                              void* d_out, int out_size, void* d_ws, size_t ws_size,
                              hipStream_t stream) {
    const float* x       = (const float*)d_in[0];
    const int*   ei      = (const int*)d_in[1];
    const float* W_lin   = (const float*)d_in[2];
    const float* b_lin   = (const float*)d_in[3];
    const float* prelu_w = (const float*)d_in[4];
    const float* W_gat   = (const float*)d_in[5];
    const float* att_src = (const float*)d_in[6];
    const float* att_dst = (const float*)d_in[7];
    // d_in[8] = gat_bias: constant per-channel shift cancelled exactly by BN
    // mean-subtraction -> skipped.
    const float* bn_gamma = (const float*)d_in[9];
    const float* bn_beta  = (const float*)d_in[10];
    float* out = (float*)d_out;

    const int N = in_sizes[0] / D;
    const int E = in_sizes[1] / 2;

    // workspace carve-up (all chunk sizes multiples of 16B)
    char* wp = (char*)d_ws;
    _Float16* hh = (_Float16*)wp;      wp += (size_t)N * D * H * sizeof(_Float16);
    float* asrc  = (float*)wp;          wp += (size_t)N * H * sizeof(float);
    float* adst  = (float*)wp;          wp += (size_t)N * H * sizeof(float);
    float* sums  = (float*)wp;          wp += 2 * D * sizeof(float);
    int* deg8    = (int*)wp;            wp += (size_t)8 * N * sizeof(int);
    int* pref8   = (int*)wp;            wp += (size_t)8 * N * sizeof(int);
    int* deg     = (int*)wp;            wp += (size_t)N * sizeof(int);
    int* offs    = (int*)wp;            wp += (size_t)N * sizeof(int);
    int* gcount  = (int*)wp;            wp += 4 * sizeof(int);
    int* rank    = (int*)wp;            wp += (size_t)E * sizeof(int);
    i32x4* recs  = (i32x4*)wp;          wp += ((size_t)E + 4) * sizeof(i32x4);
    (void)ws_size; (void)n_in; (void)out_size;

    const int total = N * D;
    const int NB = (N + 255) / 256;

    hipLaunchKernelGGL(k_node, dim3((N + 31) / 32), dim3(256), 0, stream,
                       x, W_lin, b_lin, prelu_w, W_gat, att_src, att_dst,
                       hh, asrc, adst, deg8, sums, gcount, N);
    hipLaunchKernelGGL(k_hist, dim3((E + 255) / 256), dim3(256), 0, stream,
                       ei, deg8, rank, N, E);
    hipLaunchKernelGGL(k_offsets, dim3(NB), dim3(256), 0, stream,
                       deg8, pref8, deg, gcount, offs, N);
    hipLaunchKernelGGL(k_fill, dim3((E + 255) / 256), dim3(256), 0, stream,
                       ei, offs, pref8, rank, asrc, adst, recs, N, E);
    hipLaunchKernelGGL(k_agg, dim3((N + 3) / 4), dim3(256), 0, stream,
                       asrc, adst, offs, deg, recs, (const half4_t*)hh, out, N);
    hipLaunchKernelGGL(k_bn_stats, dim3(1024), dim3(256), 0, stream,
                       out, sums, total);
    hipLaunchKernelGGL(k_bn_apply, dim3((total + 255) / 256), dim3(256), 0, stream,
                       out, sums, bn_gamma, bn_beta, total, 1.f / (float)N);
}

// Round 12
// 285.285 us; speedup vs baseline: 1.0212x; 1.0008x over previous
//
#include <hip/hip_runtime.h>
#include <hip/hip_fp16.h>

#define NEG_SLOPE 0.2f
#define BN_EPS 1e-5f

constexpr int D = 64;   // feature dim
constexpr int H = 4;    // heads

typedef _Float16 half4_t __attribute__((ext_vector_type(4)));
typedef _Float16 half8_t __attribute__((ext_vector_type(8)));
typedef float f32x4_t __attribute__((ext_vector_type(4)));
typedef int i32x4 __attribute__((ext_vector_type(4)));  // native vec for nontemporal builtins

// 16-B edge record: {src, pad, w[4]}; w = per-edge softmax numerators (4 heads)
union Rec {
    i32x4 i4;
    struct { int idx; int pad; half4_t w; } f;
};

#define MFMA16(a, b, c) __builtin_amdgcn_mfma_f32_16x16x32_f16(a, b, c, 0, 0, 0)

__device__ inline float lrelu(float v) { return (v >= 0.f) ? v : NEG_SLOPE * v; }

// load 8 consecutive fp32, split into fp16 hi + lo halves (hi+lo ~ fp32)
__device__ inline void split8(const float* p, bool ok, half8_t& hi, half8_t& lo) {
    float f[8];
    if (ok) {
        float4 a = *(const float4*)p;
        float4 b = *(const float4*)(p + 4);
        f[0] = a.x; f[1] = a.y; f[2] = a.z; f[3] = a.w;
        f[4] = b.x; f[5] = b.y; f[6] = b.z; f[7] = b.w;
    } else {
        #pragma unroll
        for (int j = 0; j < 8; j++) f[j] = 0.f;
    }
    #pragma unroll
    for (int j = 0; j < 8; j++) {
        _Float16 h = (_Float16)f[j];
        hi[j] = h;
        lo[j] = (_Float16)(f[j] - (float)h);
    }
}

// Fused MFMA node kernel, 64 nodes/block (halves per-node W traffic + split
// VALU vs 32/block): x1 = prelu(x @ W_lin^T + b_lin); h = x1 @ W_gat^T
// (split-fp16 MFMA ~ fp32); h stored fp16 layout [n][d][head]; attention dots
// from accumulators. Also zeroes deg8 slices / sums / gcount.
__global__ __launch_bounds__(256) void k_node(
    const float* __restrict__ x,
    const float* __restrict__ W_lin, const float* __restrict__ b_lin,
    const float* __restrict__ prelu_w, const float* __restrict__ W_gat,
    const float* __restrict__ att_src, const float* __restrict__ att_dst,
    _Float16* __restrict__ hh, float* __restrict__ asrc_ws,
    float* __restrict__ adst_ws, int* __restrict__ deg8,
    float* __restrict__ sums, int* __restrict__ gcount, int N)
{
    __shared__ _Float16 h_lds[64 * 256];   // 32 KB, [m][d*4+head]
    __shared__ _Float16 x1hi[64 * 72];     // 9.2 KB, row-padded (72 halves=144B)
    __shared__ _Float16 x1lo[64 * 72];

    const int t = threadIdx.x;
    const int w = t >> 6;    // wave id == head
    const int l = t & 63;
    const int li = l & 15;
    const int lq = l >> 4;
    const int base = blockIdx.x * 64;
    const int nvalid = min(64, N - base);

    // fused init: grid-stride zero of deg8 (8*N ints); block 0: sums + gcount
    {
        const int stride = gridDim.x * 256;
        for (int i = blockIdx.x * 256 + t; i < 8 * N; i += stride) deg8[i] = 0;
    }
    if (blockIdx.x == 0) {
        if (t < 2 * D) sums[t] = 0.f;
        if (t == 0) *gcount = 0;
    }

    // ---- stage A: MFMA x @ W_lin^T for cols 16w..16w+15, 4 m-tiles ----
    f32x4_t accA[4] = {};
    {
        half8_t blh[2], bll[2];
        const int n = 16 * w + li;
        #pragma unroll
        for (int ks = 0; ks < 2; ks++)
            split8(W_lin + n * 64 + 32 * ks + 8 * lq, true, blh[ks], bll[ks]);
        #pragma unroll
        for (int mt = 0; mt < 4; mt++) {
            const int row = base + 16 * mt + li;
            const bool ok = row < N;
            #pragma unroll
            for (int ks = 0; ks < 2; ks++) {
                half8_t ah, al;
                split8(x + (size_t)row * 64 + 32 * ks + 8 * lq, ok, ah, al);
                accA[mt] = MFMA16(ah, blh[ks], accA[mt]);
                accA[mt] = MFMA16(al, blh[ks], accA[mt]);
                accA[mt] = MFMA16(ah, bll[ks], accA[mt]);
            }
        }
    }
    // epilogue A: +bias, prelu, split to fp16 hi/lo in LDS
    {
        const int n = 16 * w + li;
        const float bl = b_lin[n];
        const float pw = prelu_w[n];
        #pragma unroll
        for (int mt = 0; mt < 4; mt++) {
            #pragma unroll
            for (int r = 0; r < 4; r++) {
                const int m = 16 * mt + lq * 4 + r;
                float v = accA[mt][r] + bl;
                v = (v >= 0.f) ? v : pw * v;
                _Float16 hi = (_Float16)v;
                x1hi[m * 72 + n] = hi;
                x1lo[m * 72 + n] = (_Float16)(v - (float)hi);
            }
        }
    }
    __syncthreads();

    // ---- stage B: MFMA x1 @ W_gat^T for cols 64w..64w+63, 4 m-tiles ----
    half8_t xah[4][2], xal[4][2];
    #pragma unroll
    for (int mt = 0; mt < 4; mt++) {
        #pragma unroll
        for (int ks = 0; ks < 2; ks++) {
            const int off = (16 * mt + li) * 72 + 32 * ks + 8 * lq;
            xah[mt][ks] = *(const half8_t*)(&x1hi[off]);
            xal[mt][ks] = *(const half8_t*)(&x1lo[off]);
        }
    }
    f32x4_t accB[4][4] = {};
    #pragma unroll
    for (int nt = 0; nt < 4; nt++) {
        half8_t wh[2], wl[2];
        const int c = 64 * w + 16 * nt + li;
        #pragma unroll
        for (int ks = 0; ks < 2; ks++)
            split8(W_gat + (size_t)c * 64 + 32 * ks + 8 * lq, true, wh[ks], wl[ks]);
        #pragma unroll
        for (int mt = 0; mt < 4; mt++) {
            #pragma unroll
            for (int ks = 0; ks < 2; ks++) {
                accB[mt][nt] = MFMA16(xah[mt][ks], wh[ks], accB[mt][nt]);
                accB[mt][nt] = MFMA16(xal[mt][ks], wh[ks], accB[mt][nt]);
                accB[mt][nt] = MFMA16(xah[mt][ks], wl[ks], accB[mt][nt]);
            }
        }
    }

    // ---- attention dots from registers: a[n][w] = sum_d h[n][w][d]*att[w][d]
    {
        float asv[4], adv[4];
        #pragma unroll
        for (int nt = 0; nt < 4; nt++) {
            const int c = 64 * w + 16 * nt + li;
            asv[nt] = att_src[c];
            adv[nt] = att_dst[c];
        }
        #pragma unroll
        for (int mt = 0; mt < 4; mt++) {
            #pragma unroll
            for (int r = 0; r < 4; r++) {
                float s = 0.f, dsum = 0.f;
                #pragma unroll
                for (int nt = 0; nt < 4; nt++) {
                    s += accB[mt][nt][r] * asv[nt];
                    dsum += accB[mt][nt][r] * adv[nt];
                }
                #pragma unroll
                for (int off = 1; off < 16; off <<= 1) {
                    s += __shfl_xor(s, off, 64);
                    dsum += __shfl_xor(dsum, off, 64);
                }
                if (li == 0) {
                    const int m = 16 * mt + lq * 4 + r;
                    if (m < nvalid) {
                        asrc_ws[(size_t)(base + m) * H + w] = s;
                        adst_ws[(size_t)(base + m) * H + w] = dsum;
                    }
                }
            }
        }
    }

    // ---- h -> LDS in [m][d*4+head] layout, then coalesced global write ----
    #pragma unroll
    for (int mt = 0; mt < 4; mt++) {
        #pragma unroll
        for (int nt = 0; nt < 4; nt++) {
            #pragma unroll
            for (int r = 0; r < 4; r++) {
                const int m = 16 * mt + lq * 4 + r;
                const int d = 16 * nt + li;
                h_lds[m * 256 + d * 4 + w] = (_Float16)accB[mt][nt][r];
            }
        }
    }
    __syncthreads();
    {
        const int chunks = nvalid * 32;  // 8 halves (16B) per chunk
        const uint4* src = (const uint4*)h_lds;
        uint4* dst = (uint4*)(hh + (size_t)base * 256);
        for (int i = t; i < chunks; i += 256) dst[i] = src[i];
    }
}

// ---- hist + rank, XCD-privatized ----
// p = (e>>8)&7 tracks the round-robin block->XCD mapping, so each XCD's
// atomics hit only its own deg8 slice -> no cross-XCD line ping-pong.
// atomicAdd's return IS the edge's rank within (p, dst).
__global__ __launch_bounds__(256) void k_hist(const int* __restrict__ ei,
                                              int* __restrict__ deg8,
                                              int* __restrict__ rank,
                                              int N, int E) {
    int e = blockIdx.x * 256 + threadIdx.x;
    if (e >= E) return;
    int d = ei[E + e];
    int p = (e >> 8) & 7;
    int r = atomicAdd(&deg8[p * N + d], 1);
    __builtin_nontemporal_store(r, &rank[e]);
}

// offsets: fold the 8 slices (exclusive prefix over p -> pref8, total -> deg),
// then per-block exclusive scan + one atomicAdd for the block's recs base.
__global__ __launch_bounds__(256) void k_offsets(const int* __restrict__ deg8,
                                                 int* __restrict__ pref8,
                                                 int* __restrict__ deg,
                                                 int* __restrict__ gcount,
                                                 int* __restrict__ offs, int N) {
    __shared__ int sm[256];
    __shared__ int sbase;
    int t = threadIdx.x;
    int idx = blockIdx.x * 256 + t;
    int v = 0;
    if (idx < N) {
        #pragma unroll
        for (int p = 0; p < 8; p++) {
            int c = deg8[p * N + idx];
            pref8[p * N + idx] = v;
            v += c;
        }
        deg[idx] = v;
    }
    sm[t] = v;
    __syncthreads();
    for (int off = 1; off < 256; off <<= 1) {
        int w = (t >= off) ? sm[t - off] : 0;
        __syncthreads();
        sm[t] += w;
        __syncthreads();
    }
    if (t == 255) sbase = atomicAdd(gcount, sm[255]);
    __syncthreads();
    if (idx < N) offs[idx] = sbase + sm[t] - v;  // exclusive within block + base
}

// atomic-free permute-scatter: pos = offs[dst] + pref8[p][dst] + rank.
// Computes w from the L2-resident asrc/adst tables. Plain 16-B store (L2
// coalescing of the 4 records per line beats NT here — measured R5 vs R8).
__global__ __launch_bounds__(256) void k_fill(const int* __restrict__ ei,
                                              const int* __restrict__ offs,
                                              const int* __restrict__ pref8,
                                              const int* __restrict__ rank,
                                              const float* __restrict__ asrc,
                                              const float* __restrict__ adst,
                                              i32x4* __restrict__ recs,
                                              int N, int E) {
    int e = blockIdx.x * 256 + threadIdx.x;
    if (e >= E) return;
    int s = ei[e];
    int d = ei[E + e];
    int p = (e >> 8) & 7;
    int r0 = __builtin_nontemporal_load(&rank[e]);
    int pos = offs[d] + pref8[p * N + d] + r0;
    float4 a = *(const float4*)(asrc + (size_t)s * H);
    float4 b = *(const float4*)(adst + (size_t)d * H);
    Rec r;
    r.f.idx = s;
    r.f.pad = 0;
    r.f.w[0] = (_Float16)__expf(lrelu(a.x + b.x));
    r.f.w[1] = (_Float16)__expf(lrelu(a.y + b.y));
    r.f.w[2] = (_Float16)__expf(lrelu(a.z + b.z));
    r.f.w[3] = (_Float16)__expf(lrelu(a.w + b.w));
    recs[pos] = r.i4;
}

// ---- fused softmax + aggregation: one wave per dst node (R5 best form) ----
__global__ __launch_bounds__(256) void k_agg(
    const float* __restrict__ asrc, const float* __restrict__ adst,
    const int* __restrict__ offs, const int* __restrict__ deg,
    const i32x4* __restrict__ recs, const half4_t* __restrict__ hh,
    float* __restrict__ out, int N)
{
    int wid = (blockIdx.x * 256 + threadIdx.x) >> 6;
    int lane = threadIdx.x & 63;
    if (wid >= N) return;
    const int i = wid;

    float4 b = *(const float4*)(adst + (size_t)i * H);
    float4 a0 = *(const float4*)(asrc + (size_t)i * H);
    float ws0 = __expf(lrelu(a0.x + b.x));
    float ws1 = __expf(lrelu(a0.y + b.y));
    float ws2 = __expf(lrelu(a0.z + b.z));
    float ws3 = __expf(lrelu(a0.w + b.w));

    const int beg = offs[i];
    const int dg = deg[i];

    // self-loop contribution
    float den0 = ws0, den1 = ws1, den2 = ws2, den3 = ws3;
    float acc0, acc1, acc2, acc3;
    {
        half4_t hv = hh[(size_t)i * D + lane];
        acc0 = ws0 * (float)hv[0];
        acc1 = ws1 * (float)hv[1];
        acc2 = ws2 * (float)hv[2];
        acc3 = ws3 * (float)hv[3];
    }
    int k = 0;
    for (; k + 4 <= dg; k += 4) {
        Rec r0, r1, r2, r3;
        r0.i4 = recs[beg + k];
        r1.i4 = recs[beg + k + 1];
        r2.i4 = recs[beg + k + 2];
        r3.i4 = recs[beg + k + 3];
        half4_t h0 = hh[(size_t)r0.f.idx * D + lane];
        half4_t h1 = hh[(size_t)r1.f.idx * D + lane];
        half4_t h2 = hh[(size_t)r2.f.idx * D + lane];
        half4_t h3 = hh[(size_t)r3.f.idx * D + lane];
        float w00 = (float)r0.f.w[0], w01 = (float)r0.f.w[1],
              w02 = (float)r0.f.w[2], w03 = (float)r0.f.w[3];
        float w10 = (float)r1.f.w[0], w11 = (float)r1.f.w[1],
              w12 = (float)r1.f.w[2], w13 = (float)r1.f.w[3];
        float w20 = (float)r2.f.w[0], w21 = (float)r2.f.w[1],
              w22 = (float)r2.f.w[2], w23 = (float)r2.f.w[3];
        float w30 = (float)r3.f.w[0], w31 = (float)r3.f.w[1],
              w32 = (float)r3.f.w[2], w33 = (float)r3.f.w[3];
        den0 += w00 + w10 + w20 + w30;
        den1 += w01 + w11 + w21 + w31;
        den2 += w02 + w12 + w22 + w32;
        den3 += w03 + w13 + w23 + w33;
        acc0 += w00 * (float)h0[0] + w10 * (float)h1[0] +
                w20 * (float)h2[0] + w30 * (float)h3[0];
        acc1 += w01 * (float)h0[1] + w11 * (float)h1[1] +
                w21 * (float)h2[1] + w31 * (float)h3[1];
        acc2 += w02 * (float)h0[2] + w12 * (float)h1[2] +
                w22 * (float)h2[2] + w32 * (float)h3[2];
        acc3 += w03 * (float)h0[3] + w13 * (float)h1[3] +
                w23 * (float)h2[3] + w33 * (float)h3[3];
    }
    for (; k < dg; k++) {
        Rec r;
        r.i4 = recs[beg + k];
        half4_t hv = hh[(size_t)r.f.idx * D + lane];
        float w0 = (float)r.f.w[0], w1 = (float)r.f.w[1];
        float w2 = (float)r.f.w[2], w3 = (float)r.f.w[3];
        den0 += w0; den1 += w1; den2 += w2; den3 += w3;
        acc0 += w0 * (float)hv[0];
        acc1 += w1 * (float)hv[1];
        acc2 += w2 * (float)hv[2];
        acc3 += w3 * (float)hv[3];
    }

    out[(size_t)i * D + lane] =
        0.25f * (acc0 / den0 + acc1 / den1 + acc2 / den2 + acc3 / den3);
}

// BN stats: per-channel sum & sumsq (channel = idx & 63)
__global__ __launch_bounds__(256) void k_bn_stats(const float* __restrict__ out,
                                                  float* __restrict__ sums,
                                                  int total) {
    const int t = threadIdx.x;
    const int stride = gridDim.x * 256;
    float s = 0.f, sq = 0.f;
    for (int idx = blockIdx.x * 256 + t; idx < total; idx += stride) {
        float v = out[idx];
        s += v;
        sq += v * v;
    }
    __shared__ float ls[256], lq[256];
    ls[t] = s;
    lq[t] = sq;
    __syncthreads();
    if (t < 64) {
        s = ls[t] + ls[t + 64] + ls[t + 128] + ls[t + 192];
        sq = lq[t] + lq[t + 64] + lq[t + 128] + lq[t + 192];
        atomicAdd(&sums[t], s);
        atomicAdd(&sums[64 + t], sq);
    }
}

__global__ __launch_bounds__(256) void k_bn_apply(float* __restrict__ out,
                                                  const float* __restrict__ sums,
                                                  const float* __restrict__ gamma,
                                                  const float* __restrict__ beta,
                                                  int total, float invN) {
    int idx = blockIdx.x * 256 + threadIdx.x;
    if (idx >= total) return;
    int c = idx & 63;
    float mean = sums[c] * invN;
    float var = sums[64 + c] * invN - mean * mean;
    float y = gamma[c] * (out[idx] - mean) * rsqrtf(var + BN_EPS) + beta[c];
    out[idx] = fmaxf(y, 0.f);
}

extern "C" void kernel_launch(void* const* d_in, const int* in_sizes, int n_in,
                              void* d_out, int out_size, void* d_ws, size_t ws_size,
                              hipStream_t stream) {
    const float* x       = (const float*)d_in[0];
    const int*   ei      = (const int*)d_in[1];
    const float* W_lin   = (const float*)d_in[2];
    const float* b_lin   = (const float*)d_in[3];
    const float* prelu_w = (const float*)d_in[4];
    const float* W_gat   = (const float*)d_in[5];
    const float* att_src = (const float*)d_in[6];
    const float* att_dst = (const float*)d_in[7];
    // d_in[8] = gat_bias: constant per-channel shift cancelled exactly by BN
    // mean-subtraction -> skipped.
    const float* bn_gamma = (const float*)d_in[9];
    const float* bn_beta  = (const float*)d_in[10];
    float* out = (float*)d_out;

    const int N = in_sizes[0] / D;
    const int E = in_sizes[1] / 2;

    // workspace carve-up (all chunk sizes multiples of 16B)
    char* wp = (char*)d_ws;
    _Float16* hh = (_Float16*)wp;      wp += (size_t)N * D * H * sizeof(_Float16);
    float* asrc  = (float*)wp;          wp += (size_t)N * H * sizeof(float);
    float* adst  = (float*)wp;          wp += (size_t)N * H * sizeof(float);
    float* sums  = (float*)wp;          wp += 2 * D * sizeof(float);
    int* deg8    = (int*)wp;            wp += (size_t)8 * N * sizeof(int);
    int* pref8   = (int*)wp;            wp += (size_t)8 * N * sizeof(int);
    int* deg     = (int*)wp;            wp += (size_t)N * sizeof(int);
    int* offs    = (int*)wp;            wp += (size_t)N * sizeof(int);
    int* gcount  = (int*)wp;            wp += 4 * sizeof(int);
    int* rank    = (int*)wp;            wp += (size_t)E * sizeof(int);
    i32x4* recs  = (i32x4*)wp;          wp += ((size_t)E + 4) * sizeof(i32x4);
    (void)ws_size; (void)n_in; (void)out_size;

    const int total = N * D;
    const int NB = (N + 255) / 256;

    hipLaunchKernelGGL(k_node, dim3((N + 63) / 64), dim3(256), 0, stream,
                       x, W_lin, b_lin, prelu_w, W_gat, att_src, att_dst,
                       hh, asrc, adst, deg8, sums, gcount, N);
    hipLaunchKernelGGL(k_hist, dim3((E + 255) / 256), dim3(256), 0, stream,
                       ei, deg8, rank, N, E);
    hipLaunchKernelGGL(k_offsets, dim3(NB), dim3(256), 0, stream,
                       deg8, pref8, deg, gcount, offs, N);
    hipLaunchKernelGGL(k_fill, dim3((E + 255) / 256), dim3(256), 0, stream,
                       ei, offs, pref8, rank, asrc, adst, recs, N, E);
    hipLaunchKernelGGL(k_agg, dim3((N + 3) / 4), dim3(256), 0, stream,
                       asrc, adst, offs, deg, recs, (const half4_t*)hh, out, N);
    hipLaunchKernelGGL(k_bn_stats, dim3(1024), dim3(256), 0, stream,
                       out, sums, total);
    hipLaunchKernelGGL(k_bn_apply, dim3((total + 255) / 256), dim3(256), 0, stream,
                       out, sums, bn_gamma, bn_beta, total, 1.f / (float)N);
}

// Round 13
// 273.654 us; speedup vs baseline: 1.0646x; 1.0425x over previous
//
#include <hip/hip_runtime.h>
#include <hip/hip_fp16.h>

#define NEG_SLOPE 0.2f
#define BN_EPS 1e-5f

constexpr int D = 64;   // feature dim
constexpr int H = 4;    // heads

typedef _Float16 half4_t __attribute__((ext_vector_type(4)));
typedef _Float16 half8_t __attribute__((ext_vector_type(8)));
typedef float f32x4_t __attribute__((ext_vector_type(4)));
typedef int i32x4 __attribute__((ext_vector_type(4)));  // native vec for nontemporal builtins

// 16-B edge record: {src, pad, w[4]}; w = per-edge softmax numerators (4 heads)
union Rec {
    i32x4 i4;
    struct { int idx; int pad; half4_t w; } f;
};

#define MFMA16(a, b, c) __builtin_amdgcn_mfma_f32_16x16x32_f16(a, b, c, 0, 0, 0)

__device__ inline float lrelu(float v) { return (v >= 0.f) ? v : NEG_SLOPE * v; }

// load 8 consecutive fp32, split into fp16 hi + lo halves (hi+lo ~ fp32)
__device__ inline void split8(const float* p, bool ok, half8_t& hi, half8_t& lo) {
    float f[8];
    if (ok) {
        float4 a = *(const float4*)p;
        float4 b = *(const float4*)(p + 4);
        f[0] = a.x; f[1] = a.y; f[2] = a.z; f[3] = a.w;
        f[4] = b.x; f[5] = b.y; f[6] = b.z; f[7] = b.w;
    } else {
        #pragma unroll
        for (int j = 0; j < 8; j++) f[j] = 0.f;
    }
    #pragma unroll
    for (int j = 0; j < 8; j++) {
        _Float16 h = (_Float16)f[j];
        hi[j] = h;
        lo[j] = (_Float16)(f[j] - (float)h);
    }
}

// Fused MFMA node kernel, 64 nodes/block, with the edge histogram fused in as
// an independent grid-stride prelude (deg8/sums/gcount pre-zeroed by
// hipMemsetAsync — no intra-kernel ordering needed).
// x1 = prelu(x @ W_lin^T + b_lin); h = x1 @ W_gat^T (split-fp16 MFMA ~ fp32);
// h stored fp16 layout [n][d][head]; attention dots from accumulators.
__global__ __launch_bounds__(256) void k_node(
    const float* __restrict__ x,
    const float* __restrict__ W_lin, const float* __restrict__ b_lin,
    const float* __restrict__ prelu_w, const float* __restrict__ W_gat,
    const float* __restrict__ att_src, const float* __restrict__ att_dst,
    _Float16* __restrict__ hh, float* __restrict__ asrc_ws,
    float* __restrict__ adst_ws, const int* __restrict__ ei,
    int* __restrict__ deg8, int* __restrict__ rank, int N, int E)
{
    __shared__ _Float16 h_lds[64 * 256];   // 32 KB, [m][d*4+head]
    __shared__ _Float16 x1hi[64 * 72];     // 9.2 KB, row-padded (72 halves=144B)
    __shared__ _Float16 x1lo[64 * 72];

    const int t = threadIdx.x;
    const int w = t >> 6;    // wave id == head
    const int l = t & 63;
    const int li = l & 15;
    const int lq = l >> 4;
    const int base = blockIdx.x * 64;
    const int nvalid = min(64, N - base);

    // ---- fused hist prelude (independent of node math; counters pre-zeroed)
    // p = (e>>8)&7 XCD-privatized slices; atomic return = rank within (p,dst).
    {
        const int stride = gridDim.x * 256;
        for (int e = blockIdx.x * 256 + t; e < E; e += stride) {
            int d = ei[E + e];
            int p = (e >> 8) & 7;
            int r = atomicAdd(&deg8[p * N + d], 1);
            rank[e] = r;
        }
    }

    // ---- stage A: MFMA x @ W_lin^T for cols 16w..16w+15, 4 m-tiles ----
    f32x4_t accA[4] = {};
    {
        half8_t blh[2], bll[2];
        const int n = 16 * w + li;
        #pragma unroll
        for (int ks = 0; ks < 2; ks++)
            split8(W_lin + n * 64 + 32 * ks + 8 * lq, true, blh[ks], bll[ks]);
        #pragma unroll
        for (int mt = 0; mt < 4; mt++) {
            const int row = base + 16 * mt + li;
            const bool ok = row < N;
            #pragma unroll
            for (int ks = 0; ks < 2; ks++) {
                half8_t ah, al;
                split8(x + (size_t)row * 64 + 32 * ks + 8 * lq, ok, ah, al);
                accA[mt] = MFMA16(ah, blh[ks], accA[mt]);
                accA[mt] = MFMA16(al, blh[ks], accA[mt]);
                accA[mt] = MFMA16(ah, bll[ks], accA[mt]);
            }
        }
    }
    // epilogue A: +bias, prelu, split to fp16 hi/lo in LDS
    {
        const int n = 16 * w + li;
        const float bl = b_lin[n];
        const float pw = prelu_w[n];
        #pragma unroll
        for (int mt = 0; mt < 4; mt++) {
            #pragma unroll
            for (int r = 0; r < 4; r++) {
                const int m = 16 * mt + lq * 4 + r;
                float v = accA[mt][r] + bl;
                v = (v >= 0.f) ? v : pw * v;
                _Float16 hi = (_Float16)v;
                x1hi[m * 72 + n] = hi;
                x1lo[m * 72 + n] = (_Float16)(v - (float)hi);
            }
        }
    }
    __syncthreads();

    // ---- stage B: MFMA x1 @ W_gat^T for cols 64w..64w+63, 4 m-tiles ----
    half8_t xah[4][2], xal[4][2];
    #pragma unroll
    for (int mt = 0; mt < 4; mt++) {
        #pragma unroll
        for (int ks = 0; ks < 2; ks++) {
            const int off = (16 * mt + li) * 72 + 32 * ks + 8 * lq;
            xah[mt][ks] = *(const half8_t*)(&x1hi[off]);
            xal[mt][ks] = *(const half8_t*)(&x1lo[off]);
        }
    }
    f32x4_t accB[4][4] = {};
    #pragma unroll
    for (int nt = 0; nt < 4; nt++) {
        half8_t wh[2], wl[2];
        const int c = 64 * w + 16 * nt + li;
        #pragma unroll
        for (int ks = 0; ks < 2; ks++)
            split8(W_gat + (size_t)c * 64 + 32 * ks + 8 * lq, true, wh[ks], wl[ks]);
        #pragma unroll
        for (int mt = 0; mt < 4; mt++) {
            #pragma unroll
            for (int ks = 0; ks < 2; ks++) {
                accB[mt][nt] = MFMA16(xah[mt][ks], wh[ks], accB[mt][nt]);
                accB[mt][nt] = MFMA16(xal[mt][ks], wh[ks], accB[mt][nt]);
                accB[mt][nt] = MFMA16(xah[mt][ks], wl[ks], accB[mt][nt]);
            }
        }
    }

    // ---- attention dots from registers: a[n][w] = sum_d h[n][w][d]*att[w][d]
    {
        float asv[4], adv[4];
        #pragma unroll
        for (int nt = 0; nt < 4; nt++) {
            const int c = 64 * w + 16 * nt + li;
            asv[nt] = att_src[c];
            adv[nt] = att_dst[c];
        }
        #pragma unroll
        for (int mt = 0; mt < 4; mt++) {
            #pragma unroll
            for (int r = 0; r < 4; r++) {
                float s = 0.f, dsum = 0.f;
                #pragma unroll
                for (int nt = 0; nt < 4; nt++) {
                    s += accB[mt][nt][r] * asv[nt];
                    dsum += accB[mt][nt][r] * adv[nt];
                }
                #pragma unroll
                for (int off = 1; off < 16; off <<= 1) {
                    s += __shfl_xor(s, off, 64);
                    dsum += __shfl_xor(dsum, off, 64);
                }
                if (li == 0) {
                    const int m = 16 * mt + lq * 4 + r;
                    if (m < nvalid) {
                        asrc_ws[(size_t)(base + m) * H + w] = s;
                        adst_ws[(size_t)(base + m) * H + w] = dsum;
                    }
                }
            }
        }
    }

    // ---- h -> LDS in [m][d*4+head] layout, then coalesced global write ----
    #pragma unroll
    for (int mt = 0; mt < 4; mt++) {
        #pragma unroll
        for (int nt = 0; nt < 4; nt++) {
            #pragma unroll
            for (int r = 0; r < 4; r++) {
                const int m = 16 * mt + lq * 4 + r;
                const int d = 16 * nt + li;
                h_lds[m * 256 + d * 4 + w] = (_Float16)accB[mt][nt][r];
            }
        }
    }
    __syncthreads();
    {
        const int chunks = nvalid * 32;  // 8 halves (16B) per chunk
        const uint4* src = (const uint4*)h_lds;
        uint4* dst = (uint4*)(hh + (size_t)base * 256);
        for (int i = t; i < chunks; i += 256) dst[i] = src[i];
    }
}

// offsets: fold the 8 slices (exclusive prefix over p -> pref8, total -> deg),
// then per-block exclusive scan + one atomicAdd for the block's recs base.
__global__ __launch_bounds__(256) void k_offsets(const int* __restrict__ deg8,
                                                 int* __restrict__ pref8,
                                                 int* __restrict__ deg,
                                                 int* __restrict__ gcount,
                                                 int* __restrict__ offs, int N) {
    __shared__ int sm[256];
    __shared__ int sbase;
    int t = threadIdx.x;
    int idx = blockIdx.x * 256 + t;
    int v = 0;
    if (idx < N) {
        #pragma unroll
        for (int p = 0; p < 8; p++) {
            int c = deg8[p * N + idx];
            pref8[p * N + idx] = v;
            v += c;
        }
        deg[idx] = v;
    }
    sm[t] = v;
    __syncthreads();
    for (int off = 1; off < 256; off <<= 1) {
        int w = (t >= off) ? sm[t - off] : 0;
        __syncthreads();
        sm[t] += w;
        __syncthreads();
    }
    if (t == 255) sbase = atomicAdd(gcount, sm[255]);
    __syncthreads();
    if (idx < N) offs[idx] = sbase + sm[t] - v;  // exclusive within block + base
}

// atomic-free permute-scatter: pos = offs[dst] + pref8[p][dst] + rank.
// Computes w from the L2-resident asrc/adst tables. Plain 16-B store (L2
// coalescing of the 4 records per line beats NT here — measured R5 vs R8).
__global__ __launch_bounds__(256) void k_fill(const int* __restrict__ ei,
                                              const int* __restrict__ offs,
                                              const int* __restrict__ pref8,
                                              const int* __restrict__ rank,
                                              const float* __restrict__ asrc,
                                              const float* __restrict__ adst,
                                              i32x4* __restrict__ recs,
                                              int N, int E) {
    int e = blockIdx.x * 256 + threadIdx.x;
    if (e >= E) return;
    int s = ei[e];
    int d = ei[E + e];
    int p = (e >> 8) & 7;
    int r0 = rank[e];
    int pos = offs[d] + pref8[p * N + d] + r0;
    float4 a = *(const float4*)(asrc + (size_t)s * H);
    float4 b = *(const float4*)(adst + (size_t)d * H);
    Rec r;
    r.f.idx = s;
    r.f.pad = 0;
    r.f.w[0] = (_Float16)__expf(lrelu(a.x + b.x));
    r.f.w[1] = (_Float16)__expf(lrelu(a.y + b.y));
    r.f.w[2] = (_Float16)__expf(lrelu(a.z + b.z));
    r.f.w[3] = (_Float16)__expf(lrelu(a.w + b.w));
    recs[pos] = r.i4;
}

// ---- fused softmax + aggregation: one wave per dst node (R5 best form) ----
__global__ __launch_bounds__(256) void k_agg(
    const float* __restrict__ asrc, const float* __restrict__ adst,
    const int* __restrict__ offs, const int* __restrict__ deg,
    const i32x4* __restrict__ recs, const half4_t* __restrict__ hh,
    float* __restrict__ out, int N)
{
    int wid = (blockIdx.x * 256 + threadIdx.x) >> 6;
    int lane = threadIdx.x & 63;
    if (wid >= N) return;
    const int i = wid;

    float4 b = *(const float4*)(adst + (size_t)i * H);
    float4 a0 = *(const float4*)(asrc + (size_t)i * H);
    float ws0 = __expf(lrelu(a0.x + b.x));
    float ws1 = __expf(lrelu(a0.y + b.y));
    float ws2 = __expf(lrelu(a0.z + b.z));
    float ws3 = __expf(lrelu(a0.w + b.w));

    const int beg = offs[i];
    const int dg = deg[i];

    // self-loop contribution
    float den0 = ws0, den1 = ws1, den2 = ws2, den3 = ws3;
    float acc0, acc1, acc2, acc3;
    {
        half4_t hv = hh[(size_t)i * D + lane];
        acc0 = ws0 * (float)hv[0];
        acc1 = ws1 * (float)hv[1];
        acc2 = ws2 * (float)hv[2];
        acc3 = ws3 * (float)hv[3];
    }
    int k = 0;
    for (; k + 4 <= dg; k += 4) {
        Rec r0, r1, r2, r3;
        r0.i4 = recs[beg + k];
        r1.i4 = recs[beg + k + 1];
        r2.i4 = recs[beg + k + 2];
        r3.i4 = recs[beg + k + 3];
        half4_t h0 = hh[(size_t)r0.f.idx * D + lane];
        half4_t h1 = hh[(size_t)r1.f.idx * D + lane];
        half4_t h2 = hh[(size_t)r2.f.idx * D + lane];
        half4_t h3 = hh[(size_t)r3.f.idx * D + lane];
        float w00 = (float)r0.f.w[0], w01 = (float)r0.f.w[1],
              w02 = (float)r0.f.w[2], w03 = (float)r0.f.w[3];
        float w10 = (float)r1.f.w[0], w11 = (float)r1.f.w[1],
              w12 = (float)r1.f.w[2], w13 = (float)r1.f.w[3];
        float w20 = (float)r2.f.w[0], w21 = (float)r2.f.w[1],
              w22 = (float)r2.f.w[2], w23 = (float)r2.f.w[3];
        float w30 = (float)r3.f.w[0], w31 = (float)r3.f.w[1],
              w32 = (float)r3.f.w[2], w33 = (float)r3.f.w[3];
        den0 += w00 + w10 + w20 + w30;
        den1 += w01 + w11 + w21 + w31;
        den2 += w02 + w12 + w22 + w32;
        den3 += w03 + w13 + w23 + w33;
        acc0 += w00 * (float)h0[0] + w10 * (float)h1[0] +
                w20 * (float)h2[0] + w30 * (float)h3[0];
        acc1 += w01 * (float)h0[1] + w11 * (float)h1[1] +
                w21 * (float)h2[1] + w31 * (float)h3[1];
        acc2 += w02 * (float)h0[2] + w12 * (float)h1[2] +
                w22 * (float)h2[2] + w32 * (float)h3[2];
        acc3 += w03 * (float)h0[3] + w13 * (float)h1[3] +
                w23 * (float)h2[3] + w33 * (float)h3[3];
    }
    for (; k < dg; k++) {
        Rec r;
        r.i4 = recs[beg + k];
        half4_t hv = hh[(size_t)r.f.idx * D + lane];
        float w0 = (float)r.f.w[0], w1 = (float)r.f.w[1];
        float w2 = (float)r.f.w[2], w3 = (float)r.f.w[3];
        den0 += w0; den1 += w1; den2 += w2; den3 += w3;
        acc0 += w0 * (float)hv[0];
        acc1 += w1 * (float)hv[1];
        acc2 += w2 * (float)hv[2];
        acc3 += w3 * (float)hv[3];
    }

    out[(size_t)i * D + lane] =
        0.25f * (acc0 / den0 + acc1 / den1 + acc2 / den2 + acc3 / den3);
}

// BN stats: per-channel sum & sumsq (channel = idx & 63)
__global__ __launch_bounds__(256) void k_bn_stats(const float* __restrict__ out,
                                                  float* __restrict__ sums,
                                                  int total) {
    const int t = threadIdx.x;
    const int stride = gridDim.x * 256;
    float s = 0.f, sq = 0.f;
    for (int idx = blockIdx.x * 256 + t; idx < total; idx += stride) {
        float v = out[idx];
        s += v;
        sq += v * v;
    }
    __shared__ float ls[256], lq[256];
    ls[t] = s;
    lq[t] = sq;
    __syncthreads();
    if (t < 64) {
        s = ls[t] + ls[t + 64] + ls[t + 128] + ls[t + 192];
        sq = lq[t] + lq[t + 64] + lq[t + 128] + lq[t + 192];
        atomicAdd(&sums[t], s);
        atomicAdd(&sums[64 + t], sq);
    }
}

__global__ __launch_bounds__(256) void k_bn_apply(float* __restrict__ out,
                                                  const float* __restrict__ sums,
                                                  const float* __restrict__ gamma,
                                                  const float* __restrict__ beta,
                                                  int total, float invN) {
    int idx = blockIdx.x * 256 + threadIdx.x;
    if (idx >= total) return;
    int c = idx & 63;
    float mean = sums[c] * invN;
    float var = sums[64 + c] * invN - mean * mean;
    float y = gamma[c] * (out[idx] - mean) * rsqrtf(var + BN_EPS) + beta[c];
    out[idx] = fmaxf(y, 0.f);
}

extern "C" void kernel_launch(void* const* d_in, const int* in_sizes, int n_in,
                              void* d_out, int out_size, void* d_ws, size_t ws_size,
                              hipStream_t stream) {
    const float* x       = (const float*)d_in[0];
    const int*   ei      = (const int*)d_in[1];
    const float* W_lin   = (const float*)d_in[2];
    const float* b_lin   = (const float*)d_in[3];
    const float* prelu_w = (const float*)d_in[4];
    const float* W_gat   = (const float*)d_in[5];
    const float* att_src = (const float*)d_in[6];
    const float* att_dst = (const float*)d_in[7];
    // d_in[8] = gat_bias: constant per-channel shift cancelled exactly by BN
    // mean-subtraction -> skipped.
    const float* bn_gamma = (const float*)d_in[9];
    const float* bn_beta  = (const float*)d_in[10];
    float* out = (float*)d_out;

    const int N = in_sizes[0] / D;
    const int E = in_sizes[1] / 2;

    // workspace carve-up (all chunk sizes multiples of 16B).
    // sums + deg8 + gcount are CONTIGUOUS so one hipMemsetAsync zeroes all.
    char* wp = (char*)d_ws;
    _Float16* hh = (_Float16*)wp;      wp += (size_t)N * D * H * sizeof(_Float16);
    float* asrc  = (float*)wp;          wp += (size_t)N * H * sizeof(float);
    float* adst  = (float*)wp;          wp += (size_t)N * H * sizeof(float);
    char* zero_base = wp;
    float* sums  = (float*)wp;          wp += 2 * D * sizeof(float);
    int* deg8    = (int*)wp;            wp += (size_t)8 * N * sizeof(int);
    int* gcount  = (int*)wp;            wp += 4 * sizeof(int);
    size_t zero_bytes = (size_t)(wp - zero_base);
    int* pref8   = (int*)wp;            wp += (size_t)8 * N * sizeof(int);
    int* deg     = (int*)wp;            wp += (size_t)N * sizeof(int);
    int* offs    = (int*)wp;            wp += (size_t)N * sizeof(int);
    int* rank    = (int*)wp;            wp += (size_t)E * sizeof(int);
    i32x4* recs  = (i32x4*)wp;          wp += ((size_t)E + 4) * sizeof(i32x4);
    (void)ws_size; (void)n_in; (void)out_size;

    const int total = N * D;
    const int NB = (N + 255) / 256;

    hipMemsetAsync(zero_base, 0, zero_bytes, stream);
    hipLaunchKernelGGL(k_node, dim3((N + 63) / 64), dim3(256), 0, stream,
                       x, W_lin, b_lin, prelu_w, W_gat, att_src, att_dst,
                       hh, asrc, adst, ei, deg8, rank, N, E);
    hipLaunchKernelGGL(k_offsets, dim3(NB), dim3(256), 0, stream,
                       deg8, pref8, deg, gcount, offs, N);
    hipLaunchKernelGGL(k_fill, dim3((E + 255) / 256), dim3(256), 0, stream,
                       ei, offs, pref8, rank, asrc, adst, recs, N, E);
    hipLaunchKernelGGL(k_agg, dim3((N + 3) / 4), dim3(256), 0, stream,
                       asrc, adst, offs, deg, recs, (const half4_t*)hh, out, N);
    hipLaunchKernelGGL(k_bn_stats, dim3(1024), dim3(256), 0, stream,
                       out, sums, total);
    hipLaunchKernelGGL(k_bn_apply, dim3((total + 255) / 256), dim3(256), 0, stream,
                       out, sums, bn_gamma, bn_beta, total, 1.f / (float)N);
}

// Round 14
// 267.976 us; speedup vs baseline: 1.0872x; 1.0212x over previous
//
#include <hip/hip_runtime.h>
#include <hip/hip_fp16.h>

#define NEG_SLOPE 0.2f
#define BN_EPS 1e-5f

constexpr int D = 64;   // feature dim
constexpr int H = 4;    // heads

typedef _Float16 half4_t __attribute__((ext_vector_type(4)));
typedef _Float16 half8_t __attribute__((ext_vector_type(8)));
typedef float f32x4_t __attribute__((ext_vector_type(4)));
typedef int i32x4 __attribute__((ext_vector_type(4)));  // native vec for nontemporal builtins

// 16-B edge record: {src, pad, w[4]}; w = per-edge softmax numerators (4 heads)
union Rec {
    i32x4 i4;
    struct { int idx; int pad; half4_t w; } f;
};

#define MFMA16(a, b, c) __builtin_amdgcn_mfma_f32_16x16x32_f16(a, b, c, 0, 0, 0)

__device__ inline float lrelu(float v) { return (v >= 0.f) ? v : NEG_SLOPE * v; }

// load 8 consecutive fp32, split into fp16 hi + lo halves (hi+lo ~ fp32)
__device__ inline void split8(const float* p, bool ok, half8_t& hi, half8_t& lo) {
    float f[8];
    if (ok) {
        float4 a = *(const float4*)p;
        float4 b = *(const float4*)(p + 4);
        f[0] = a.x; f[1] = a.y; f[2] = a.z; f[3] = a.w;
        f[4] = b.x; f[5] = b.y; f[6] = b.z; f[7] = b.w;
    } else {
        #pragma unroll
        for (int j = 0; j < 8; j++) f[j] = 0.f;
    }
    #pragma unroll
    for (int j = 0; j < 8; j++) {
        _Float16 h = (_Float16)f[j];
        hi[j] = h;
        lo[j] = (_Float16)(f[j] - (float)h);
    }
}

// Fused MFMA node kernel, 32 nodes/block (26 KB LDS -> 6 blocks/CU: occupancy
// for the latency-bound hist prelude), hist fused as independent grid-stride
// prelude (deg8/sums/gcount pre-zeroed by hipMemsetAsync).
// x1 = prelu(x @ W_lin^T + b_lin); h = x1 @ W_gat^T (split-fp16 MFMA ~ fp32);
// h stored fp16 layout [n][d][head]; attention dots from accumulators.
__global__ __launch_bounds__(256) void k_node(
    const float* __restrict__ x,
    const float* __restrict__ W_lin, const float* __restrict__ b_lin,
    const float* __restrict__ prelu_w, const float* __restrict__ W_gat,
    const float* __restrict__ att_src, const float* __restrict__ att_dst,
    _Float16* __restrict__ hh, float* __restrict__ asrc_ws,
    float* __restrict__ adst_ws, const int* __restrict__ ei,
    int* __restrict__ deg8, int* __restrict__ rank, int N, int E)
{
    // h_lds rows padded to 264 halves (528 B = 132 dwords = 4 mod 32 banks):
    // kills the 4-way write conflict of the unpadded 512-B stride (now 2-way,
    // which is free on CDNA4). 264 halves = 33 uint4 per row for copy-out.
    __shared__ _Float16 h_lds[32 * 264];   // 16.5 KB
    __shared__ _Float16 x1hi[32 * 72];     // 4.5 KB, row-padded (72 halves=144B)
    __shared__ _Float16 x1lo[32 * 72];

    const int t = threadIdx.x;
    const int w = t >> 6;    // wave id == head
    const int l = t & 63;
    const int li = l & 15;
    const int lq = l >> 4;
    const int base = blockIdx.x * 32;
    const int nvalid = min(32, N - base);

    // ---- fused hist prelude (independent of node math; counters pre-zeroed)
    // p = (e>>8)&7 XCD-privatized slices; atomic return = rank within (p,dst).
    // Grid = 1563 blocks -> 400k threads -> ~2 edges/thread.
    {
        const int stride = gridDim.x * 256;
        for (int e = blockIdx.x * 256 + t; e < E; e += stride) {
            int d = ei[E + e];
            int p = (e >> 8) & 7;
            int r = atomicAdd(&deg8[p * N + d], 1);
            rank[e] = r;
        }
    }

    // ---- stage A: MFMA x @ W_lin^T for cols 16w..16w+15, 2 m-tiles ----
    f32x4_t accA[2] = {};
    {
        half8_t blh[2], bll[2];
        const int n = 16 * w + li;
        #pragma unroll
        for (int ks = 0; ks < 2; ks++)
            split8(W_lin + n * 64 + 32 * ks + 8 * lq, true, blh[ks], bll[ks]);
        #pragma unroll
        for (int mt = 0; mt < 2; mt++) {
            const int row = base + 16 * mt + li;
            const bool ok = row < N;
            #pragma unroll
            for (int ks = 0; ks < 2; ks++) {
                half8_t ah, al;
                split8(x + (size_t)row * 64 + 32 * ks + 8 * lq, ok, ah, al);
                accA[mt] = MFMA16(ah, blh[ks], accA[mt]);
                accA[mt] = MFMA16(al, blh[ks], accA[mt]);
                accA[mt] = MFMA16(ah, bll[ks], accA[mt]);
            }
        }
    }
    // epilogue A: +bias, prelu, split to fp16 hi/lo in LDS
    {
        const int n = 16 * w + li;
        const float bl = b_lin[n];
        const float pw = prelu_w[n];
        #pragma unroll
        for (int mt = 0; mt < 2; mt++) {
            #pragma unroll
            for (int r = 0; r < 4; r++) {
                const int m = 16 * mt + lq * 4 + r;
                float v = accA[mt][r] + bl;
                v = (v >= 0.f) ? v : pw * v;
                _Float16 hi = (_Float16)v;
                x1hi[m * 72 + n] = hi;
                x1lo[m * 72 + n] = (_Float16)(v - (float)hi);
            }
        }
    }
    __syncthreads();

    // ---- stage B: MFMA x1 @ W_gat^T for cols 64w..64w+63, 2 m-tiles ----
    half8_t xah[2][2], xal[2][2];
    #pragma unroll
    for (int mt = 0; mt < 2; mt++) {
        #pragma unroll
        for (int ks = 0; ks < 2; ks++) {
            const int off = (16 * mt + li) * 72 + 32 * ks + 8 * lq;
            xah[mt][ks] = *(const half8_t*)(&x1hi[off]);
            xal[mt][ks] = *(const half8_t*)(&x1lo[off]);
        }
    }
    f32x4_t accB[2][4] = {};
    #pragma unroll
    for (int nt = 0; nt < 4; nt++) {
        half8_t wh[2], wl[2];
        const int c = 64 * w + 16 * nt + li;
        #pragma unroll
        for (int ks = 0; ks < 2; ks++)
            split8(W_gat + (size_t)c * 64 + 32 * ks + 8 * lq, true, wh[ks], wl[ks]);
        #pragma unroll
        for (int mt = 0; mt < 2; mt++) {
            #pragma unroll
            for (int ks = 0; ks < 2; ks++) {
                accB[mt][nt] = MFMA16(xah[mt][ks], wh[ks], accB[mt][nt]);
                accB[mt][nt] = MFMA16(xal[mt][ks], wh[ks], accB[mt][nt]);
                accB[mt][nt] = MFMA16(xah[mt][ks], wl[ks], accB[mt][nt]);
            }
        }
    }

    // ---- attention dots from registers: a[n][w] = sum_d h[n][w][d]*att[w][d]
    {
        float asv[4], adv[4];
        #pragma unroll
        for (int nt = 0; nt < 4; nt++) {
            const int c = 64 * w + 16 * nt + li;
            asv[nt] = att_src[c];
            adv[nt] = att_dst[c];
        }
        #pragma unroll
        for (int mt = 0; mt < 2; mt++) {
            #pragma unroll
            for (int r = 0; r < 4; r++) {
                float s = 0.f, dsum = 0.f;
                #pragma unroll
                for (int nt = 0; nt < 4; nt++) {
                    s += accB[mt][nt][r] * asv[nt];
                    dsum += accB[mt][nt][r] * adv[nt];
                }
                #pragma unroll
                for (int off = 1; off < 16; off <<= 1) {
                    s += __shfl_xor(s, off, 64);
                    dsum += __shfl_xor(dsum, off, 64);
                }
                if (li == 0) {
                    const int m = 16 * mt + lq * 4 + r;
                    if (m < nvalid) {
                        asrc_ws[(size_t)(base + m) * H + w] = s;
                        adst_ws[(size_t)(base + m) * H + w] = dsum;
                    }
                }
            }
        }
    }

    // ---- h -> LDS in padded [m][264] layout, then coalesced global write ----
    #pragma unroll
    for (int mt = 0; mt < 2; mt++) {
        #pragma unroll
        for (int nt = 0; nt < 4; nt++) {
            #pragma unroll
            for (int r = 0; r < 4; r++) {
                const int m = 16 * mt + lq * 4 + r;
                const int d = 16 * nt + li;
                h_lds[m * 264 + d * 4 + w] = (_Float16)accB[mt][nt][r];
            }
        }
    }
    __syncthreads();
    {
        const int chunks = nvalid * 32;  // 8 halves (16B) per chunk
        const uint4* src = (const uint4*)h_lds;
        uint4* dst = (uint4*)(hh + (size_t)base * 256);
        for (int i = t; i < chunks; i += 256) {
            int row = i >> 5;
            int col = i & 31;
            dst[i] = src[row * 33 + col];  // padded row = 33 uint4
        }
    }
}

// offsets: fold the 8 slices (exclusive prefix over p -> pref8, total -> deg),
// then per-block exclusive scan + one atomicAdd for the block's recs base.
__global__ __launch_bounds__(256) void k_offsets(const int* __restrict__ deg8,
                                                 int* __restrict__ pref8,
                                                 int* __restrict__ deg,
                                                 int* __restrict__ gcount,
                                                 int* __restrict__ offs, int N) {
    __shared__ int sm[256];
    __shared__ int sbase;
    int t = threadIdx.x;
    int idx = blockIdx.x * 256 + t;
    int v = 0;
    if (idx < N) {
        #pragma unroll
        for (int p = 0; p < 8; p++) {
            int c = deg8[p * N + idx];
            pref8[p * N + idx] = v;
            v += c;
        }
        deg[idx] = v;
    }
    sm[t] = v;
    __syncthreads();
    for (int off = 1; off < 256; off <<= 1) {
        int w = (t >= off) ? sm[t - off] : 0;
        __syncthreads();
        sm[t] += w;
        __syncthreads();
    }
    if (t == 255) sbase = atomicAdd(gcount, sm[255]);
    __syncthreads();
    if (idx < N) offs[idx] = sbase + sm[t] - v;  // exclusive within block + base
}

// atomic-free permute-scatter: pos = offs[dst] + pref8[p][dst] + rank.
// Computes w from the L2-resident asrc/adst tables. Plain 16-B store (L2
// coalescing of the 4 records per line beats NT here — measured R5 vs R8).
__global__ __launch_bounds__(256) void k_fill(const int* __restrict__ ei,
                                              const int* __restrict__ offs,
                                              const int* __restrict__ pref8,
                                              const int* __restrict__ rank,
                                              const float* __restrict__ asrc,
                                              const float* __restrict__ adst,
                                              i32x4* __restrict__ recs,
                                              int N, int E) {
    int e = blockIdx.x * 256 + threadIdx.x;
    if (e >= E) return;
    int s = ei[e];
    int d = ei[E + e];
    int p = (e >> 8) & 7;
    int r0 = rank[e];
    int pos = offs[d] + pref8[p * N + d] + r0;
    float4 a = *(const float4*)(asrc + (size_t)s * H);
    float4 b = *(const float4*)(adst + (size_t)d * H);
    Rec r;
    r.f.idx = s;
    r.f.pad = 0;
    r.f.w[0] = (_Float16)__expf(lrelu(a.x + b.x));
    r.f.w[1] = (_Float16)__expf(lrelu(a.y + b.y));
    r.f.w[2] = (_Float16)__expf(lrelu(a.z + b.z));
    r.f.w[3] = (_Float16)__expf(lrelu(a.w + b.w));
    recs[pos] = r.i4;
}

// ---- fused softmax + aggregation: one wave per dst node (R5 best form) ----
__global__ __launch_bounds__(256) void k_agg(
    const float* __restrict__ asrc, const float* __restrict__ adst,
    const int* __restrict__ offs, const int* __restrict__ deg,
    const i32x4* __restrict__ recs, const half4_t* __restrict__ hh,
    float* __restrict__ out, int N)
{
    int wid = (blockIdx.x * 256 + threadIdx.x) >> 6;
    int lane = threadIdx.x & 63;
    if (wid >= N) return;
    const int i = wid;

    float4 b = *(const float4*)(adst + (size_t)i * H);
    float4 a0 = *(const float4*)(asrc + (size_t)i * H);
    float ws0 = __expf(lrelu(a0.x + b.x));
    float ws1 = __expf(lrelu(a0.y + b.y));
    float ws2 = __expf(lrelu(a0.z + b.z));
    float ws3 = __expf(lrelu(a0.w + b.w));

    const int beg = offs[i];
    const int dg = deg[i];

    // self-loop contribution
    float den0 = ws0, den1 = ws1, den2 = ws2, den3 = ws3;
    float acc0, acc1, acc2, acc3;
    {
        half4_t hv = hh[(size_t)i * D + lane];
        acc0 = ws0 * (float)hv[0];
        acc1 = ws1 * (float)hv[1];
        acc2 = ws2 * (float)hv[2];
        acc3 = ws3 * (float)hv[3];
    }
    int k = 0;
    for (; k + 4 <= dg; k += 4) {
        Rec r0, r1, r2, r3;
        r0.i4 = recs[beg + k];
        r1.i4 = recs[beg + k + 1];
        r2.i4 = recs[beg + k + 2];
        r3.i4 = recs[beg + k + 3];
        half4_t h0 = hh[(size_t)r0.f.idx * D + lane];
        half4_t h1 = hh[(size_t)r1.f.idx * D + lane];
        half4_t h2 = hh[(size_t)r2.f.idx * D + lane];
        half4_t h3 = hh[(size_t)r3.f.idx * D + lane];
        float w00 = (float)r0.f.w[0], w01 = (float)r0.f.w[1],
              w02 = (float)r0.f.w[2], w03 = (float)r0.f.w[3];
        float w10 = (float)r1.f.w[0], w11 = (float)r1.f.w[1],
              w12 = (float)r1.f.w[2], w13 = (float)r1.f.w[3];
        float w20 = (float)r2.f.w[0], w21 = (float)r2.f.w[1],
              w22 = (float)r2.f.w[2], w23 = (float)r2.f.w[3];
        float w30 = (float)r3.f.w[0], w31 = (float)r3.f.w[1],
              w32 = (float)r3.f.w[2], w33 = (float)r3.f.w[3];
        den0 += w00 + w10 + w20 + w30;
        den1 += w01 + w11 + w21 + w31;
        den2 += w02 + w12 + w22 + w32;
        den3 += w03 + w13 + w23 + w33;
        acc0 += w00 * (float)h0[0] + w10 * (float)h1[0] +
                w20 * (float)h2[0] + w30 * (float)h3[0];
        acc1 += w01 * (float)h0[1] + w11 * (float)h1[1] +
                w21 * (float)h2[1] + w31 * (float)h3[1];
        acc2 += w02 * (float)h0[2] + w12 * (float)h1[2] +
                w22 * (float)h2[2] + w32 * (float)h3[2];
        acc3 += w03 * (float)h0[3] + w13 * (float)h1[3] +
                w23 * (float)h2[3] + w33 * (float)h3[3];
    }
    for (; k < dg; k++) {
        Rec r;
        r.i4 = recs[beg + k];
        half4_t hv = hh[(size_t)r.f.idx * D + lane];
        float w0 = (float)r.f.w[0], w1 = (float)r.f.w[1];
        float w2 = (float)r.f.w[2], w3 = (float)r.f.w[3];
        den0 += w0; den1 += w1; den2 += w2; den3 += w3;
        acc0 += w0 * (float)hv[0];
        acc1 += w1 * (float)hv[1];
        acc2 += w2 * (float)hv[2];
        acc3 += w3 * (float)hv[3];
    }

    out[(size_t)i * D + lane] =
        0.25f * (acc0 / den0 + acc1 / den1 + acc2 / den2 + acc3 / den3);
}

// BN stats: per-channel sum & sumsq (channel = idx & 63)
__global__ __launch_bounds__(256) void k_bn_stats(const float* __restrict__ out,
                                                  float* __restrict__ sums,
                                                  int total) {
    const int t = threadIdx.x;
    const int stride = gridDim.x * 256;
    float s = 0.f, sq = 0.f;
    for (int idx = blockIdx.x * 256 + t; idx < total; idx += stride) {
        float v = out[idx];
        s += v;
        sq += v * v;
    }
    __shared__ float ls[256], lq[256];
    ls[t] = s;
    lq[t] = sq;
    __syncthreads();
    if (t < 64) {
        s = ls[t] + ls[t + 64] + ls[t + 128] + ls[t + 192];
        sq = lq[t] + lq[t + 64] + lq[t + 128] + lq[t + 192];
        atomicAdd(&sums[t], s);
        atomicAdd(&sums[64 + t], sq);
    }
}

__global__ __launch_bounds__(256) void k_bn_apply(float* __restrict__ out,
                                                  const float* __restrict__ sums,
                                                  const float* __restrict__ gamma,
                                                  const float* __restrict__ beta,
                                                  int total, float invN) {
    int idx = blockIdx.x * 256 + threadIdx.x;
    if (idx >= total) return;
    int c = idx & 63;
    float mean = sums[c] * invN;
    float var = sums[64 + c] * invN - mean * mean;
    float y = gamma[c] * (out[idx] - mean) * rsqrtf(var + BN_EPS) + beta[c];
    out[idx] = fmaxf(y, 0.f);
}

extern "C" void kernel_launch(void* const* d_in, const int* in_sizes, int n_in,
                              void* d_out, int out_size, void* d_ws, size_t ws_size,
                              hipStream_t stream) {
    const float* x       = (const float*)d_in[0];
    const int*   ei      = (const int*)d_in[1];
    const float* W_lin   = (const float*)d_in[2];
    const float* b_lin   = (const float*)d_in[3];
    const float* prelu_w = (const float*)d_in[4];
    const float* W_gat   = (const float*)d_in[5];
    const float* att_src = (const float*)d_in[6];
    const float* att_dst = (const float*)d_in[7];
    // d_in[8] = gat_bias: constant per-channel shift cancelled exactly by BN
    // mean-subtraction -> skipped.
    const float* bn_gamma = (const float*)d_in[9];
    const float* bn_beta  = (const float*)d_in[10];
    float* out = (float*)d_out;

    const int N = in_sizes[0] / D;
    const int E = in_sizes[1] / 2;

    // workspace carve-up (all chunk sizes multiples of 16B).
    // sums + deg8 + gcount are CONTIGUOUS so one hipMemsetAsync zeroes all.
    char* wp = (char*)d_ws;
    _Float16* hh = (_Float16*)wp;      wp += (size_t)N * D * H * sizeof(_Float16);
    float* asrc  = (float*)wp;          wp += (size_t)N * H * sizeof(float);
    float* adst  = (float*)wp;          wp += (size_t)N * H * sizeof(float);
    char* zero_base = wp;
    float* sums  = (float*)wp;          wp += 2 * D * sizeof(float);
    int* deg8    = (int*)wp;            wp += (size_t)8 * N * sizeof(int);
    int* gcount  = (int*)wp;            wp += 4 * sizeof(int);
    size_t zero_bytes = (size_t)(wp - zero_base);
    int* pref8   = (int*)wp;            wp += (size_t)8 * N * sizeof(int);
    int* deg     = (int*)wp;            wp += (size_t)N * sizeof(int);
    int* offs    = (int*)wp;            wp += (size_t)N * sizeof(int);
    int* rank    = (int*)wp;            wp += (size_t)E * sizeof(int);
    i32x4* recs  = (i32x4*)wp;          wp += ((size_t)E + 4) * sizeof(i32x4);
    (void)ws_size; (void)n_in; (void)out_size;

    const int total = N * D;
    const int NB = (N + 255) / 256;

    hipMemsetAsync(zero_base, 0, zero_bytes, stream);
    hipLaunchKernelGGL(k_node, dim3((N + 31) / 32), dim3(256), 0, stream,
                       x, W_lin, b_lin, prelu_w, W_gat, att_src, att_dst,
                       hh, asrc, adst, ei, deg8, rank, N, E);
    hipLaunchKernelGGL(k_offsets, dim3(NB), dim3(256), 0, stream,
                       deg8, pref8, deg, gcount, offs, N);
    hipLaunchKernelGGL(k_fill, dim3((E + 255) / 256), dim3(256), 0, stream,
                       ei, offs, pref8, rank, asrc, adst, recs, N, E);
    hipLaunchKernelGGL(k_agg, dim3((N + 3) / 4), dim3(256), 0, stream,
                       asrc, adst, offs, deg, recs, (const half4_t*)hh, out, N);
    hipLaunchKernelGGL(k_bn_stats, dim3(1024), dim3(256), 0, stream,
                       out, sums, total);
    hipLaunchKernelGGL(k_bn_apply, dim3((total + 255) / 256), dim3(256), 0, stream,
                       out, sums, bn_gamma, bn_beta, total, 1.f / (float)N);
}